// Round 8
// baseline (386.177 us; speedup 1.0000x reference)
//
#include <hip/hip_runtime.h>
#include <math.h>

// ---------------- problem constants ----------------
#define ED    1024
#define GH    1024
#define NLAY  3
#define NHEAD 8
#define HD    128
#define NNODE 2048
#define BQ    1024
#define CAP   192
#define CAPP  208   // CAP padded to multiple of 16

typedef unsigned short u16;
typedef __attribute__((ext_vector_type(8))) short short8;
typedef __attribute__((ext_vector_type(4))) float f32x4;

// ---------------- workspace layout (float units) ----------------
static const size_t OFF_X    = 0;         // [2048][1024] fp32
static const size_t OFF_XB   = 2097152;   // bf16 shadow
static const size_t OFF_WHB  = 3145728;   // [2048][1024] bf16 Wh
static const size_t OFF_WTG  = 4194304;   // [3][1024][1024] bf16 gatW^T
static const size_t OFF_WTPO = 5767168;   // [1024][1024] bf16
static const size_t OFF_WTQ1 = 6291456;
static const size_t OFF_WTD1 = 6815744;
static const size_t OFF_WTQ2 = 7340032;
static const size_t OFF_WTD2 = 7864320;
static const size_t OFF_G    = 8388608;   // [2048][1024] fp32
static const size_t OFF_GT   = 10485760;  // [1024][2048] bf16 (epilogue-written)
static const size_t OFF_QPB  = 11534336;  // [2048][1024] bf16 q|d
static const size_t OFF_HF   = 12582912;  // [2048][1024] fp32
static const size_t OFF_HB   = 14680064;  // bf16
static const size_t OFF_FF   = 15728640;  // [2048][1024] fp32
static const size_t OFF_FB   = 17825792;  // bf16 normalized
static const size_t OFF_NEG  = 18874368;  // [1024][1024] fp32
static const size_t OFF_SV1  = 19922944;  // [8][2048] s1
static const size_t OFF_SV2  = 19939328;  // [8][2048] s2
static const size_t OFF_ACC  = 19955712;  // [0]=lap [1]=nce
static const size_t OFF_CNT  = 19955714;  // int completion counter
static const size_t OFF_NCNT = 19955720;  // int*
static const size_t OFF_NBR  = 19957768;  // int*

// ---------------- helpers ----------------
__device__ __forceinline__ u16 f2bf(float f) {
  unsigned int u = __float_as_uint(f);
  return (u16)((u + 0x7fffu + ((u >> 16) & 1u)) >> 16);
}
__device__ __forceinline__ float bf2f(u16 u) {
  return __uint_as_float(((unsigned int)u) << 16);
}

__device__ __forceinline__ float waveSum(float v) {
#pragma unroll
  for (int off = 32; off; off >>= 1) v += __shfl_xor(v, off, 64);
  return v;
}
__device__ __forceinline__ float waveMax(float v) {
#pragma unroll
  for (int off = 32; off; off >>= 1) v = fmaxf(v, __shfl_xor(v, off, 64));
  return v;
}
__device__ __forceinline__ float blockSum(float v) {
  __shared__ float buf[4];
  int lane = threadIdx.x & 63, wid = threadIdx.x >> 6, nw = (blockDim.x + 63) >> 6;
  v = waveSum(v);
  __syncthreads();
  if (lane == 0) buf[wid] = v;
  __syncthreads();
  float r = buf[0];
  for (int i = 1; i < nw; ++i) r += buf[i];
  return r;
}
__device__ __forceinline__ float blockMax(float v) {
  __shared__ float buf[4];
  int lane = threadIdx.x & 63, wid = threadIdx.x >> 6, nw = (blockDim.x + 63) >> 6;
  v = waveMax(v);
  __syncthreads();
  if (lane == 0) buf[wid] = v;
  __syncthreads();
  float r = buf[0];
  for (int i = 1; i < nw; ++i) r = fmaxf(r, buf[i]);
  return r;
}

// ------------- core 128x128 bf16 MFMA GEMM (round-4 pipeline, verified) ----
__global__ __launch_bounds__(256) void gemm128(
    const u16* __restrict__ A, const u16* __restrict__ B0,
    const u16* __restrict__ B1, float* __restrict__ C, u16* __restrict__ Cb,
    u16* __restrict__ Ct,
    const float* __restrict__ bias0, const float* __restrict__ bias1,
    int M, int N, int K, int split, float scale) {
  __shared__ u16 As[2][128][32];
  __shared__ u16 Bs[2][128][32];
  const int tid = threadIdx.x, wave = tid >> 6, lane = tid & 63;
  const int bm = blockIdx.y * 128, bn = blockIdx.x * 128;
  const u16* Bt = (bm < split) ? B0 : B1;
  const float* bias = (bm < split) ? bias0 : bias1;

  const int sr = tid >> 2, ss = tid & 3;
  const u16* ga0 = A  + (size_t)(bm + sr) * K + ss * 8;
  const u16* ga1 = A  + (size_t)(bm + sr + 64) * K + ss * 8;
  const u16* gb0 = Bt + (size_t)(bn + sr) * K + ss * 8;
  const u16* gb1 = Bt + (size_t)(bn + sr + 64) * K + ss * 8;

  const int r16 = lane & 15, kg = lane >> 4;
  const int wm = (wave >> 1) * 64, wn = (wave & 1) * 64;

  f32x4 acc[4][4] = {};
  const int nk = K >> 5;

  float4 pa0 = *(const float4*)ga0;
  float4 pa1 = *(const float4*)ga1;
  float4 pb0 = *(const float4*)gb0;
  float4 pb1 = *(const float4*)gb1;

  for (int kt = 0; kt < nk; ++kt) {
    const int p = kt & 1;
    *(float4*)&As[p][sr][ss * 8]      = pa0;
    *(float4*)&As[p][sr + 64][ss * 8] = pa1;
    *(float4*)&Bs[p][sr][ss * 8]      = pb0;
    *(float4*)&Bs[p][sr + 64][ss * 8] = pb1;
    __syncthreads();
    if (kt + 1 < nk) {
      ga0 += 32; ga1 += 32; gb0 += 32; gb1 += 32;
      pa0 = *(const float4*)ga0;
      pa1 = *(const float4*)ga1;
      pb0 = *(const float4*)gb0;
      pb1 = *(const float4*)gb1;
    }
    short8 av[4], bv[4];
#pragma unroll
    for (int i = 0; i < 4; ++i)
      av[i] = *(const short8*)&As[p][wm + i * 16 + r16][kg * 8];
#pragma unroll
    for (int j = 0; j < 4; ++j)
      bv[j] = *(const short8*)&Bs[p][wn + j * 16 + r16][kg * 8];
#pragma unroll
    for (int i = 0; i < 4; ++i)
#pragma unroll
      for (int j = 0; j < 4; ++j)
        acc[i][j] = __builtin_amdgcn_mfma_f32_16x16x32_bf16(av[i], bv[j], acc[i][j], 0, 0, 0);
  }

  if (C) {
#pragma unroll
    for (int j = 0; j < 4; ++j) {
      int col = bn + wn + j * 16 + r16;
      float bvv = bias ? bias[col] : 0.f;
#pragma unroll
      for (int i = 0; i < 4; ++i) {
        int row0 = bm + wm + i * 16 + kg * 4;
        float* cp = C + (size_t)row0 * N + col;
#pragma unroll
        for (int r = 0; r < 4; ++r)
          cp[(size_t)r * N] = acc[i][j][r] * scale + bvv;
      }
    }
  }
  if (Cb) {
#pragma unroll
    for (int j = 0; j < 4; ++j) {
      int col = bn + wn + j * 16 + r16;
      float bvv = bias ? bias[col] : 0.f;
#pragma unroll
      for (int i = 0; i < 4; ++i) {
        int row0 = bm + wm + i * 16 + kg * 4;
        u16* cp = Cb + (size_t)row0 * N + col;
#pragma unroll
        for (int r = 0; r < 4; ++r)
          cp[(size_t)r * N] = f2bf(acc[i][j][r] * scale + bvv);
      }
    }
  }
  if (Ct) {
#pragma unroll
    for (int j = 0; j < 4; ++j) {
      int col = bn + wn + j * 16 + r16;
      float bvv = bias ? bias[col] : 0.f;
#pragma unroll
      for (int i = 0; i < 4; ++i) {
        int row0 = bm + wm + i * 16 + kg * 4;
        ushort4 o;
        o.x = f2bf(acc[i][j][0] * scale + bvv);
        o.y = f2bf(acc[i][j][1] * scale + bvv);
        o.z = f2bf(acc[i][j][2] * scale + bvv);
        o.w = f2bf(acc[i][j][3] * scale + bvv);
        *(ushort4*)&Ct[(size_t)col * M + row0] = o;
      }
    }
  }
}

// ------------- dual-problem GEMM (z selects); problem 0 may emit s1/s2 -----
__global__ __launch_bounds__(256) void gemm_dual(
    const u16* __restrict__ A0, const u16* __restrict__ B00,
    const u16* __restrict__ B01, float* __restrict__ C0, u16* __restrict__ D0,
    const float* __restrict__ e0, const float* __restrict__ f0, int M0, int sp0, float sc0,
    const float* __restrict__ A1v, const float* __restrict__ A2v,
    float* __restrict__ S1o, float* __restrict__ S2o,
    const u16* __restrict__ A1, const u16* __restrict__ B10,
    const u16* __restrict__ B11, float* __restrict__ C1, u16* __restrict__ D1,
    const float* __restrict__ e1, const float* __restrict__ f1, int M1, int sp1, float sc1) {
  const int z = blockIdx.z;
  const u16* A   = z ? A1 : A0;
  const u16* Bt0 = z ? B10 : B00;
  const u16* Bt1 = z ? B11 : B01;
  float* C = z ? C1 : C0;
  u16*   D = z ? D1 : D0;
  const float* bias0 = z ? e1 : e0;
  const float* bias1 = z ? f1 : f0;
  const int M = z ? M1 : M0, split = z ? sp1 : sp0;
  const float scale = z ? sc1 : sc0;
  const int bm = blockIdx.y * 128, bn = blockIdx.x * 128;
  if (bm >= M) return;
  const int N = 1024, K = 1024;
  const u16* Bt = (bm < split) ? Bt0 : Bt1;
  const float* bias = (bm < split) ? bias0 : bias1;

  __shared__ u16 As[2][128][32];
  __shared__ u16 Bs[2][128][32];
  const int tid = threadIdx.x, wave = tid >> 6, lane = tid & 63;
  const int sr = tid >> 2, ss = tid & 3;
  const u16* ga0 = A  + (size_t)(bm + sr) * K + ss * 8;
  const u16* ga1 = A  + (size_t)(bm + sr + 64) * K + ss * 8;
  const u16* gb0 = Bt + (size_t)(bn + sr) * K + ss * 8;
  const u16* gb1 = Bt + (size_t)(bn + sr + 64) * K + ss * 8;
  const int r16 = lane & 15, kg = lane >> 4;
  const int wm = (wave >> 1) * 64, wn = (wave & 1) * 64;

  f32x4 acc[4][4] = {};
  const int nk = 32;

  float4 pa0 = *(const float4*)ga0;
  float4 pa1 = *(const float4*)ga1;
  float4 pb0 = *(const float4*)gb0;
  float4 pb1 = *(const float4*)gb1;

  for (int kt = 0; kt < nk; ++kt) {
    const int p = kt & 1;
    *(float4*)&As[p][sr][ss * 8]      = pa0;
    *(float4*)&As[p][sr + 64][ss * 8] = pa1;
    *(float4*)&Bs[p][sr][ss * 8]      = pb0;
    *(float4*)&Bs[p][sr + 64][ss * 8] = pb1;
    __syncthreads();
    if (kt + 1 < nk) {
      ga0 += 32; ga1 += 32; gb0 += 32; gb1 += 32;
      pa0 = *(const float4*)ga0;
      pa1 = *(const float4*)ga1;
      pb0 = *(const float4*)gb0;
      pb1 = *(const float4*)gb1;
    }
    short8 av[4], bv[4];
#pragma unroll
    for (int i = 0; i < 4; ++i)
      av[i] = *(const short8*)&As[p][wm + i * 16 + r16][kg * 8];
#pragma unroll
    for (int j = 0; j < 4; ++j)
      bv[j] = *(const short8*)&Bs[p][wn + j * 16 + r16][kg * 8];
#pragma unroll
    for (int i = 0; i < 4; ++i)
#pragma unroll
      for (int j = 0; j < 4; ++j)
        acc[i][j] = __builtin_amdgcn_mfma_f32_16x16x32_bf16(av[i], bv[j], acc[i][j], 0, 0, 0);
  }

  if (C) {
#pragma unroll
    for (int j = 0; j < 4; ++j) {
      int col = bn + wn + j * 16 + r16;
      float bvv = bias ? bias[col] : 0.f;
#pragma unroll
      for (int i = 0; i < 4; ++i) {
        int row0 = bm + wm + i * 16 + kg * 4;
        float* cp = C + (size_t)row0 * N + col;
#pragma unroll
        for (int r = 0; r < 4; ++r)
          cp[(size_t)r * N] = acc[i][j][r] * scale + bvv;
      }
    }
  }
  if (D) {
#pragma unroll
    for (int j = 0; j < 4; ++j) {
      int col = bn + wn + j * 16 + r16;
      float bvv = bias ? bias[col] : 0.f;
#pragma unroll
      for (int i = 0; i < 4; ++i) {
        int row0 = bm + wm + i * 16 + kg * 4;
        u16* cp = D + (size_t)row0 * N + col;
#pragma unroll
        for (int r = 0; r < 4; ++r)
          cp[(size_t)r * N] = f2bf(acc[i][j][r] * scale + bvv);
      }
    }
  }

  if (z == 0 && S1o) {
    float c1[4], c2[4];
#pragma unroll
    for (int j = 0; j < 4; ++j) {
      int col = bn + wn + j * 16 + r16;
      c1[j] = A1v[col]; c2[j] = A2v[col];
    }
    float r1[4][4], r2[4][4];
#pragma unroll
    for (int i = 0; i < 4; ++i)
#pragma unroll
      for (int r = 0; r < 4; ++r) {
        float v1 = 0.f, v2 = 0.f;
#pragma unroll
        for (int j = 0; j < 4; ++j) {
          v1 += acc[i][j][r] * c1[j];
          v2 += acc[i][j][r] * c2[j];
        }
#pragma unroll
        for (int off = 8; off; off >>= 1) {
          v1 += __shfl_xor(v1, off, 64);
          v2 += __shfl_xor(v2, off, 64);
        }
        r1[i][r] = v1; r2[i][r] = v2;
      }
    __syncthreads();
    float* sb1 = (float*)&As[0][0][0];
    float* sb2 = sb1 + 256;
    if (r16 == 0) {
      int half = wn >> 6;
#pragma unroll
      for (int i = 0; i < 4; ++i)
#pragma unroll
        for (int r = 0; r < 4; ++r) {
          int row = wm + i * 16 + kg * 4 + r;
          sb1[half * 128 + row] = r1[i][r];
          sb2[half * 128 + row] = r2[i][r];
        }
    }
    __syncthreads();
    if (tid < 128) {
      int h = blockIdx.x;
      S1o[(h << 11) + bm + tid] = sb1[tid] + sb1[128 + tid];
      S2o[(h << 11) + bm + tid] = sb2[tid] + sb2[128 + tid];
    }
  }
}

// ------------- lap GEMM v3: split-K=8, XCD swizzle, conflict-free staging,
// fused dot with G, folded finalization via completion counter -------------
// 1024 linear blocks: bn = n>>7 (8), strip = n&127 -> bm = (strip&15)*128,
// k0 = (strip>>4)*256. Blocks sharing an A strip have equal n%8 (same XCD).
__global__ __launch_bounds__(256) void lap_gemm(
    const float* __restrict__ A, const u16* __restrict__ Bt,
    const float* __restrict__ G, float* __restrict__ acc,
    int* __restrict__ cnt_done, float* __restrict__ out) {
  __shared__ u16 As[2][128][32];
  __shared__ u16 Bs[2][128][32];
  const int tid = threadIdx.x, wave = tid >> 6, lane = tid & 63;
  const int n = blockIdx.x;
  const int bn = (n >> 7) * 128, strip = n & 127;
  const int bm = (strip & 15) * 128, k0 = (strip >> 4) * 256;

  const int sr = tid >> 2, ss = tid & 3;
  const float* gA0 = A + (size_t)(bm + sr) * NNODE + k0 + ss * 8;
  const float* gA1 = gA0 + (size_t)64 * NNODE;
  const u16* gb0 = Bt + (size_t)(bn + sr) * NNODE + k0 + ss * 8;
  const u16* gb1 = Bt + (size_t)(bn + sr + 64) * NNODE + k0 + ss * 8;

  const int r16 = lane & 15, kg = lane >> 4;
  const int wm = (wave >> 1) * 64, wn = (wave & 1) * 64;

  f32x4 acc_r[4][4] = {};
  const int nk = 8;   // 256 / 32

  float4 a0l = *(const float4*)gA0, a0h = *(const float4*)(gA0 + 4);
  float4 a1l = *(const float4*)gA1, a1h = *(const float4*)(gA1 + 4);
  float4 pb0 = *(const float4*)gb0;
  float4 pb1 = *(const float4*)gb1;

  for (int kt = 0; kt < nk; ++kt) {
    const int p = kt & 1;
    {
      union { short8 v; ushort4 u4[2]; } w;
      w.u4[0].x = f2bf(a0l.x); w.u4[0].y = f2bf(a0l.y);
      w.u4[0].z = f2bf(a0l.z); w.u4[0].w = f2bf(a0l.w);
      w.u4[1].x = f2bf(a0h.x); w.u4[1].y = f2bf(a0h.y);
      w.u4[1].z = f2bf(a0h.z); w.u4[1].w = f2bf(a0h.w);
      *(short8*)&As[p][sr][ss * 8] = w.v;          // lane-linear 16B: conflict-free
      w.u4[0].x = f2bf(a1l.x); w.u4[0].y = f2bf(a1l.y);
      w.u4[0].z = f2bf(a1l.z); w.u4[0].w = f2bf(a1l.w);
      w.u4[1].x = f2bf(a1h.x); w.u4[1].y = f2bf(a1h.y);
      w.u4[1].z = f2bf(a1h.z); w.u4[1].w = f2bf(a1h.w);
      *(short8*)&As[p][sr + 64][ss * 8] = w.v;
    }
    *(float4*)&Bs[p][sr][ss * 8]      = pb0;
    *(float4*)&Bs[p][sr + 64][ss * 8] = pb1;
    __syncthreads();
    if (kt + 1 < nk) {
      gA0 += 32; gA1 += 32; gb0 += 32; gb1 += 32;
      a0l = *(const float4*)gA0; a0h = *(const float4*)(gA0 + 4);
      a1l = *(const float4*)gA1; a1h = *(const float4*)(gA1 + 4);
      pb0 = *(const float4*)gb0;
      pb1 = *(const float4*)gb1;
    }
    short8 av[4], bv[4];
#pragma unroll
    for (int i = 0; i < 4; ++i)
      av[i] = *(const short8*)&As[p][wm + i * 16 + r16][kg * 8];
#pragma unroll
    for (int j = 0; j < 4; ++j)
      bv[j] = *(const short8*)&Bs[p][wn + j * 16 + r16][kg * 8];
#pragma unroll
    for (int i = 0; i < 4; ++i)
#pragma unroll
      for (int j = 0; j < 4; ++j)
        acc_r[i][j] = __builtin_amdgcn_mfma_f32_16x16x32_bf16(av[i], bv[j], acc_r[i][j], 0, 0, 0);
  }

  float sum = 0.f;
#pragma unroll
  for (int j = 0; j < 4; ++j) {
    int col = bn + wn + j * 16 + r16;
#pragma unroll
    for (int i = 0; i < 4; ++i) {
      int row0 = bm + wm + i * 16 + kg * 4;
      const float* gp = G + (size_t)row0 * ED + col;
#pragma unroll
      for (int r = 0; r < 4; ++r)
        sum += acc_r[i][j][r] * gp[(size_t)r * ED];
    }
  }
  sum = blockSum(sum);
  if (tid == 0) {
    atomicAdd(acc, sum);
    __threadfence();
    int prev = atomicAdd(cnt_done, 1);
    if (prev == (int)gridDim.x - 1) {   // last block: finalize output
      float lap  = atomicAdd(acc, 0.f) / 2048.f;
      float info = atomicAdd(acc + 1, 0.f) / 1024.f;
      out[0] = info + 0.1f * lap;
      out[1] = info;
      out[2] = lap;
    }
  }
}

// ------------- fused GAT attention + layer elementwise tail ----------------
// blocks [0,2048): attention (32 thr/head, parallel softmax, 16-deep gather)
// blocks [2048, ...): mode 0 = ln_gelu rows, 1 = l2norm rows, 2 = lse rows
__global__ __launch_bounds__(256) void att_elem(
    const u16* __restrict__ WHb, const float* __restrict__ S1,
    const float* __restrict__ S2, const int* __restrict__ nbr,
    const int* __restrict__ ncnt, float* __restrict__ X, u16* __restrict__ Xb,
    const float* __restrict__ g, const float* __restrict__ b,
    int mode, const float* __restrict__ EIN, u16* __restrict__ EOUT,
    const float* __restrict__ g0, const float* __restrict__ b0,
    const float* __restrict__ g1, const float* __restrict__ b1,
    float* __restrict__ acc) {
  const int t = threadIdx.x;
  if (blockIdx.x < NNODE) {
    // ---- attention part
    __shared__ int snb[CAPP];
    __shared__ float pw[NHEAD][CAPP];
    const int n = blockIdx.x;
    const int h = t >> 5, l = t & 31;
    const int cnt = ncnt[n];
    const int cntP = (cnt + 15) & ~15;
    for (int j = t; j < cnt; j += 256) snb[j] = nbr[n * CAP + j];
    __syncthreads();
    for (int j = cnt + t; j < cntP; j += 256) snb[j] = snb[0];

    const float s1v = S1[(h << 11) + n];
    float ev[6];
    float lmax = -1e30f;
    int ne = 0;
    for (int j = l; j < cnt; j += 32) {
      float e = s1v + S2[(h << 11) + snb[j]];
      e = e > 0.f ? e : 0.2f * e;
      ev[ne++] = e;
      lmax = fmaxf(lmax, e);
    }
#pragma unroll
    for (int off = 16; off; off >>= 1) lmax = fmaxf(lmax, __shfl_xor(lmax, off, 64));
    float lsum = 0.f;
    ne = 0;
    for (int j = l; j < cnt; j += 32) {
      float p = __expf(ev[ne++] - lmax);
      pw[h][j] = p;
      lsum += p;
    }
    for (int j = cnt + l; j < cntP; j += 32) pw[h][j] = 0.f;
#pragma unroll
    for (int off = 16; off; off >>= 1) lsum += __shfl_xor(lsum, off, 64);
    const float inv = 1.f / lsum;
    __syncthreads();

    float o0 = 0.f, o1 = 0.f, o2 = 0.f, o3 = 0.f;
    const u16* wp = WHb + (t << 2);
    for (int j0 = 0; j0 < cntP; j0 += 16) {
      ushort4 buf[16];
#pragma unroll
      for (int u = 0; u < 16; ++u)
        buf[u] = *(const ushort4*)(wp + ((size_t)snb[j0 + u] << 10));
#pragma unroll
      for (int u = 0; u < 16; ++u) {
        float w = pw[h][j0 + u];
        o0 += w * bf2f(buf[u].x);
        o1 += w * bf2f(buf[u].y);
        o2 += w * bf2f(buf[u].z);
        o3 += w * bf2f(buf[u].w);
      }
    }
    o0 *= inv; o1 *= inv; o2 *= inv; o3 *= inv;

    float s  = o0 + o1 + o2 + o3;
    float sq = o0 * o0 + o1 * o1 + o2 * o2 + o3 * o3;
    float mean = blockSum(s) * (1.f / 1024.f);
    float var  = blockSum(sq) * (1.f / 1024.f) - mean * mean;
    float rstd = rsqrtf(fmaxf(var, 0.f) + 1e-5f);
    float4 xv = *(float4*)&X[((size_t)n << 10) + (t << 2)];
    float ov[4] = {o0, o1, o2, o3};
    float xa[4] = {xv.x, xv.y, xv.z, xv.w};
#pragma unroll
    for (int i = 0; i < 4; ++i) {
      int c = (t << 2) + i;
      float y = (ov[i] - mean) * rstd * g[c] + b[c];
      y = y > 0.f ? y : expm1f(y);
      xa[i] += y;
    }
    *(float4*)&X[((size_t)n << 10) + (t << 2)] = make_float4(xa[0], xa[1], xa[2], xa[3]);
    ushort4 o;
    o.x = f2bf(xa[0]); o.y = f2bf(xa[1]); o.z = f2bf(xa[2]); o.w = f2bf(xa[3]);
    *(ushort4*)&Xb[((size_t)n << 10) + (t << 2)] = o;
  } else {
    const int row = blockIdx.x - NNODE;
    if (mode == 0) {
      // ln_gelu
      const float* gg = (row < 1024) ? g0 : g1;
      const float* bb = (row < 1024) ? b0 : b1;
      float4 v = *(const float4*)&EIN[((size_t)row << 10) + (t << 2)];
      float s = v.x + v.y + v.z + v.w;
      float sq = v.x * v.x + v.y * v.y + v.z * v.z + v.w * v.w;
      float mean = blockSum(s) * (1.f / 1024.f);
      float var = blockSum(sq) * (1.f / 1024.f) - mean * mean;
      float rstd = rsqrtf(fmaxf(var, 0.f) + 1e-5f);
      float vals[4] = {v.x, v.y, v.z, v.w};
      ushort4 o;
      u16* oa = (u16*)&o;
#pragma unroll
      for (int i = 0; i < 4; ++i) {
        int c = (t << 2) + i;
        float y = (vals[i] - mean) * rstd * gg[c] + bb[c];
        y = 0.5f * y * (1.f + erff(y * 0.70710678118654752f));
        oa[i] = f2bf(y);
      }
      *(ushort4*)&EOUT[((size_t)row << 10) + (t << 2)] = o;
    } else if (mode == 1) {
      // l2norm
      float4 v = *(const float4*)&EIN[((size_t)row << 10) + (t << 2)];
      float sq = v.x * v.x + v.y * v.y + v.z * v.z + v.w * v.w;
      float s = blockSum(sq);
      float inv = 1.f / fmaxf(sqrtf(s), 1e-12f);
      ushort4 o;
      o.x = f2bf(v.x * inv); o.y = f2bf(v.y * inv);
      o.z = f2bf(v.z * inv); o.w = f2bf(v.w * inv);
      *(ushort4*)&EOUT[((size_t)row << 10) + (t << 2)] = o;
    } else {
      // lse over [pos | neg_row]
      const float* rw = EIN + ((size_t)row << 10);
      float4 v = *(const float4*)&rw[t << 2];
      float lm = fmaxf(fmaxf(v.x, v.y), fmaxf(v.z, v.w));
      float m = blockMax(lm);
      float ls = __expf(v.x - m) + __expf(v.y - m) + __expf(v.z - m) + __expf(v.w - m);
      float ssum = blockSum(ls);
      if (t == 0) {
        float pos = rw[row];
        float loss = m + logf(ssum + __expf(pos - m)) - pos;
        atomicAdd(acc + 1, loss);
      }
    }
  }
}

// ------------- prep mega-kernel: build_nbr + node cvt + q/d cvt ------------
__global__ __launch_bounds__(256) void prep_mega(
    const float* __restrict__ adj, int* __restrict__ nbr, int* __restrict__ ncnt,
    float* __restrict__ acc, int* __restrict__ cnt_done,
    const float* __restrict__ nodes, float* __restrict__ Xf, u16* __restrict__ Xb,
    const float* __restrict__ q, const float* __restrict__ d, u16* __restrict__ QPb) {
  const int bx = blockIdx.x, tid = threadIdx.x;
  if (bx < NNODE) {
    __shared__ int cnt;
    if (bx == 0 && tid < 2) acc[tid] = 0.f;
    if (bx == 0 && tid == 2) *cnt_done = 0;
    if (tid == 0) cnt = 0;
    __syncthreads();
    for (int c = tid; c < NNODE; c += 256) {
      if (adj[((size_t)bx << 11) + c] > 0.f) {
        int p = atomicAdd(&cnt, 1);
        if (p < CAP) nbr[bx * CAP + p] = c;
      }
    }
    __syncthreads();
    if (tid == 0) ncnt[bx] = cnt < CAP ? cnt : CAP;
  } else if (bx < 2 * NNODE) {
    int i = (bx - NNODE) * 256 + tid;
    float4 v = ((const float4*)nodes)[i];
    ((float4*)Xf)[i] = v;
    ushort4 o;
    o.x = f2bf(v.x); o.y = f2bf(v.y); o.z = f2bf(v.z); o.w = f2bf(v.w);
    ((ushort4*)Xb)[i] = o;
  } else {
    int i = (bx - 2 * NNODE) * 256 + tid;
    const int half = BQ * ED / 4;
    const float* src = (i < half) ? q : d;
    int j = (i < half) ? i : i - half;
    float4 v = ((const float4*)src)[j];
    ushort4 o;
    o.x = f2bf(v.x); o.y = f2bf(v.y); o.z = f2bf(v.z); o.w = f2bf(v.w);
    ((ushort4*)QPb)[i] = o;
  }
}

// ---------------- transposes ----------------
__device__ __forceinline__ void cvt_tr_body(const float* ip, u16* op, int R, int C) {
  __shared__ float T[64][65];
  int r0 = blockIdx.y * 64, c0 = blockIdx.x * 64;
  int t = threadIdx.x;
#pragma unroll
  for (int p = 0; p < 4; ++p) {
    int row = p * 16 + (t >> 4), col = (t & 15) * 4;
    float4 v = *(const float4*)&ip[(size_t)(r0 + row) * C + c0 + col];
    T[row][col] = v.x; T[row][col + 1] = v.y;
    T[row][col + 2] = v.z; T[row][col + 3] = v.w;
  }
  __syncthreads();
#pragma unroll
  for (int p = 0; p < 4; ++p) {
    int c = p * 16 + (t >> 4), r = (t & 15) * 4;
    ushort4 o;
    o.x = f2bf(T[r][c]); o.y = f2bf(T[r + 1][c]);
    o.z = f2bf(T[r + 2][c]); o.w = f2bf(T[r + 3][c]);
    *(ushort4*)&op[(size_t)(c0 + c) * R + r0 + r] = o;
  }
}

__global__ __launch_bounds__(256) void cvt_transpose(
    const float* __restrict__ in, u16* __restrict__ out,
    int R, int C, long inb, long outb) {
  cvt_tr_body(in + (size_t)blockIdx.z * inb, out + (size_t)blockIdx.z * outb, R, C);
}

__global__ __launch_bounds__(256) void cvt_transpose5(
    const float* __restrict__ i0, u16* __restrict__ o0,
    const float* __restrict__ i1, u16* __restrict__ o1,
    const float* __restrict__ i2, u16* __restrict__ o2,
    const float* __restrict__ i3, u16* __restrict__ o3,
    const float* __restrict__ i4, u16* __restrict__ o4) {
  const float* in; u16* out;
  switch (blockIdx.z) {
    case 0: in = i0; out = o0; break;
    case 1: in = i1; out = o1; break;
    case 2: in = i2; out = o2; break;
    case 3: in = i3; out = o3; break;
    default: in = i4; out = o4; break;
  }
  cvt_tr_body(in, out, 1024, 1024);
}

// ---------------- host launcher ----------------
extern "C" void kernel_launch(void* const* d_in, const int* in_sizes, int n_in,
                              void* d_out, int out_size, void* d_ws, size_t ws_size,
                              hipStream_t stream) {
  const float* query = (const float*)d_in[0];
  const float* docs  = (const float*)d_in[1];
  const float* nodes = (const float*)d_in[2];
  const float* adj   = (const float*)d_in[3];
  const float* lapl  = (const float*)d_in[4];
  const float* qW1 = (const float*)d_in[5],  *qb1 = (const float*)d_in[6];
  const float* qg  = (const float*)d_in[7],  *qbt = (const float*)d_in[8];
  const float* qW2 = (const float*)d_in[9],  *qb2 = (const float*)d_in[10];
  const float* dW1 = (const float*)d_in[11], *db1 = (const float*)d_in[12];
  const float* dg  = (const float*)d_in[13], *dbt = (const float*)d_in[14];
  const float* dW2 = (const float*)d_in[15], *db2 = (const float*)d_in[16];
  const float* gatW = (const float*)d_in[17];
  const float* a1   = (const float*)d_in[18];
  const float* a2   = (const float*)d_in[19];
  const float* ln_g = (const float*)d_in[20];
  const float* ln_b = (const float*)d_in[21];
  const float* poW  = (const float*)d_in[22];
  const float* pob  = (const float*)d_in[23];
  float* out = (float*)d_out;

  float* ws = (float*)d_ws;
  float* X    = ws + OFF_X;
  u16*   Xb   = (u16*)(ws + OFF_XB);
  u16*   WHb  = (u16*)(ws + OFF_WHB);
  u16*   WtG  = (u16*)(ws + OFF_WTG);
  u16*   WtPO = (u16*)(ws + OFF_WTPO);
  u16*   WtQ1 = (u16*)(ws + OFF_WTQ1);
  u16*   WtD1 = (u16*)(ws + OFF_WTD1);
  u16*   WtQ2 = (u16*)(ws + OFF_WTQ2);
  u16*   WtD2 = (u16*)(ws + OFF_WTD2);
  float* G    = ws + OFF_G;
  u16*   Gt   = (u16*)(ws + OFF_GT);
  u16*   QPb  = (u16*)(ws + OFF_QPB);
  float* Hf   = ws + OFF_HF;
  u16*   Hb   = (u16*)(ws + OFF_HB);
  float* Ff   = ws + OFF_FF;
  u16*   Fb   = (u16*)(ws + OFF_FB);
  float* NEG  = ws + OFF_NEG;
  float* S1v  = ws + OFF_SV1;
  float* S2v  = ws + OFF_SV2;
  float* ACC  = ws + OFF_ACC;
  int*   CNTD = (int*)(ws + OFF_CNT);
  int*   NCNT = (int*)(ws + OFF_NCNT);
  int*   NBR  = (int*)(ws + OFF_NBR);

  const size_t WSL = (size_t)GH * ED;

  // ---- prep (1 launch) + weight transposes (2)
  prep_mega<<<3 * NNODE, 256, 0, stream>>>(
      adj, NBR, NCNT, ACC, CNTD, nodes, X, Xb, query, docs, QPb);
  cvt_transpose<<<dim3(2, 16, 24), 256, 0, stream>>>(
      gatW, WtG, ED, HD, (long)ED * HD, (long)HD * ED);
  cvt_transpose5<<<dim3(16, 16, 5), 256, 0, stream>>>(
      poW, WtPO, qW1, WtQ1, dW1, WtD1, qW2, WtQ2, dW2, WtD2);

  // ---- layer 0: GAT gemm (+s1s2) paired with MLP1; att + ln_gelu merged
  gemm_dual<<<dim3(8, 16, 2), 256, 0, stream>>>(
      Xb, WtG, WtG, nullptr, WHb, nullptr, nullptr, NNODE, NNODE, 1.f,
      a1, a2, S1v, S2v,
      QPb, WtQ1, WtD1, Hf, nullptr, qb1, db1, 2 * BQ, BQ, 1.f);
  att_elem<<<NNODE + 2 * BQ, 256, 0, stream>>>(
      WHb, S1v, S2v, NBR, NCNT, X, Xb, ln_g, ln_b,
      0, Hf, Hb, qg, qbt, dg, dbt, ACC);

  // ---- layer 1: GAT gemm (+s1s2) paired with MLP2; att + l2norm merged
  gemm_dual<<<dim3(8, 16, 2), 256, 0, stream>>>(
      Xb, WtG + WSL, WtG + WSL, nullptr, WHb, nullptr, nullptr, NNODE, NNODE, 1.f,
      a1 + NHEAD * HD, a2 + NHEAD * HD, S1v, S2v,
      Hb, WtQ2, WtD2, Ff, nullptr, qb2, db2, 2 * BQ, BQ, 1.f);
  att_elem<<<NNODE + 2 * BQ, 256, 0, stream>>>(
      WHb, S1v, S2v, NBR, NCNT, X, Xb, ln_g + GH, ln_b + GH,
      1, Ff, Fb, nullptr, nullptr, nullptr, nullptr, ACC);

  // ---- layer 2: GAT gemm (+s1s2) paired with NEG; att + lse merged
  gemm_dual<<<dim3(8, 16, 2), 256, 0, stream>>>(
      Xb, WtG + 2 * WSL, WtG + 2 * WSL, nullptr, WHb, nullptr, nullptr, NNODE, NNODE, 1.f,
      a1 + 2 * NHEAD * HD, a2 + 2 * NHEAD * HD, S1v, S2v,
      Fb, Fb + (size_t)BQ * ED, Fb + (size_t)BQ * ED, NEG, nullptr,
      nullptr, nullptr, BQ, BQ, 20.f);
  att_elem<<<NNODE + BQ, 256, 0, stream>>>(
      WHb, S1v, S2v, NBR, NCNT, X, Xb, ln_g + 2 * GH, ln_b + 2 * GH,
      2, NEG, nullptr, nullptr, nullptr, nullptr, nullptr, ACC);

  // ---- graph embeds (G fp32 + Gt bf16) + laplacian (+final folded)
  gemm128<<<dim3(ED / 128, NNODE / 128), 256, 0, stream>>>(
      Xb, WtPO, WtPO, G, nullptr, Gt, pob, pob, NNODE, ED, GH, NNODE, 1.f);
  lap_gemm<<<1024, 256, 0, stream>>>(lapl, Gt, G, ACC, CNTD, out);
}

// Round 9
// 372.618 us; speedup vs baseline: 1.0364x; 1.0364x over previous
//
#include <hip/hip_runtime.h>
#include <math.h>

// ---------------- problem constants ----------------
#define ED    1024
#define GH    1024
#define NLAY  3
#define NHEAD 8
#define HD    128
#define NNODE 2048
#define BQ    1024
#define CAP   192
#define CAPP  208

typedef unsigned short u16;
typedef __attribute__((ext_vector_type(8))) short short8;
typedef __attribute__((ext_vector_type(4))) float f32x4;

// ---------------- workspace layout (float units) ----------------
static const size_t OFF_X    = 0;         // [2048][1024] fp32
static const size_t OFF_XB   = 2097152;   // bf16 shadow
static const size_t OFF_WHB  = 3145728;   // [2048][1024] bf16 Wh
static const size_t OFF_WTG  = 4194304;   // [3][1024][1024] bf16 gatW^T
static const size_t OFF_WTPO = 5767168;
static const size_t OFF_WTQ1 = 6291456;
static const size_t OFF_WTD1 = 6815744;
static const size_t OFF_WTQ2 = 7340032;
static const size_t OFF_WTD2 = 7864320;
static const size_t OFF_GB   = 8388608;   // [2048][1024] bf16 graph embeds
static const size_t OFF_QPB  = 11534336;  // [2048][1024] bf16 q|d
static const size_t OFF_HF   = 12582912;  // [2048][1024] fp32
static const size_t OFF_HB   = 14680064;  // bf16
static const size_t OFF_FF   = 15728640;  // [2048][1024] fp32
static const size_t OFF_FB   = 17825792;  // bf16 normalized
static const size_t OFF_NEG  = 18874368;  // [1024][1024] fp32
static const size_t OFF_SV1  = 19922944;  // [8][2048]
static const size_t OFF_SV2  = 19939328;
static const size_t OFF_ACC  = 19955712;  // [0]=lap [1]=nce
static const size_t OFF_CNT  = 19955714;  // int completion counter
static const size_t OFF_NCNT = 19955720;  // int*
static const size_t OFF_NBR  = 19957768;  // int*

// ---------------- helpers ----------------
__device__ __forceinline__ u16 f2bf(float f) {
  unsigned int u = __float_as_uint(f);
  return (u16)((u + 0x7fffu + ((u >> 16) & 1u)) >> 16);
}
__device__ __forceinline__ float bf2f(u16 u) {
  return __uint_as_float(((unsigned int)u) << 16);
}

__device__ __forceinline__ float waveSum(float v) {
#pragma unroll
  for (int off = 32; off; off >>= 1) v += __shfl_xor(v, off, 64);
  return v;
}
__device__ __forceinline__ float waveMax(float v) {
#pragma unroll
  for (int off = 32; off; off >>= 1) v = fmaxf(v, __shfl_xor(v, off, 64));
  return v;
}
__device__ __forceinline__ float blockSum(float v) {
  __shared__ float buf[4];
  int lane = threadIdx.x & 63, wid = threadIdx.x >> 6, nw = (blockDim.x + 63) >> 6;
  v = waveSum(v);
  __syncthreads();
  if (lane == 0) buf[wid] = v;
  __syncthreads();
  float r = buf[0];
  for (int i = 1; i < nw; ++i) r += buf[i];
  return r;
}
__device__ __forceinline__ float blockMax(float v) {
  __shared__ float buf[4];
  int lane = threadIdx.x & 63, wid = threadIdx.x >> 6, nw = (blockDim.x + 63) >> 6;
  v = waveMax(v);
  __syncthreads();
  if (lane == 0) buf[wid] = v;
  __syncthreads();
  float r = buf[0];
  for (int i = 1; i < nw; ++i) r = fmaxf(r, buf[i]);
  return r;
}

// LDS seg swizzle (round-2 verified: 0 bank conflicts on frag ds_read_b128)
#define SWZ(row, seg) (((seg) ^ (((row) >> 1) & 3)) << 3)

// ------------- core 128x128 bf16 MFMA GEMM (dbuf pipeline + swizzle) -------
__global__ __launch_bounds__(256) void gemm128(
    const u16* __restrict__ A, const u16* __restrict__ B0,
    const u16* __restrict__ B1, float* __restrict__ C, u16* __restrict__ Cb,
    const float* __restrict__ bias0, const float* __restrict__ bias1,
    int M, int N, int K, int split, float scale) {
  __shared__ u16 As[2][128][32];
  __shared__ u16 Bs[2][128][32];
  const int tid = threadIdx.x, wave = tid >> 6, lane = tid & 63;
  const int bm = blockIdx.y * 128, bn = blockIdx.x * 128;
  const u16* Bt = (bm < split) ? B0 : B1;
  const float* bias = (bm < split) ? bias0 : bias1;

  const int sr = tid >> 2, ss = tid & 3;
  const int so = SWZ(sr, ss);               // same for row sr+64 (64 ≡ 0 mod 4 after >>1&3)
  const u16* ga0 = A  + (size_t)(bm + sr) * K + ss * 8;
  const u16* ga1 = A  + (size_t)(bm + sr + 64) * K + ss * 8;
  const u16* gb0 = Bt + (size_t)(bn + sr) * K + ss * 8;
  const u16* gb1 = Bt + (size_t)(bn + sr + 64) * K + ss * 8;

  const int r16 = lane & 15, kg = lane >> 4;
  const int wm = (wave >> 1) * 64, wn = (wave & 1) * 64;

  f32x4 acc[4][4] = {};
  const int nk = K >> 5;

  float4 pa0 = *(const float4*)ga0;
  float4 pa1 = *(const float4*)ga1;
  float4 pb0 = *(const float4*)gb0;
  float4 pb1 = *(const float4*)gb1;

  for (int kt = 0; kt < nk; ++kt) {
    const int p = kt & 1;
    *(float4*)&As[p][sr][so]      = pa0;
    *(float4*)&As[p][sr + 64][so] = pa1;
    *(float4*)&Bs[p][sr][so]      = pb0;
    *(float4*)&Bs[p][sr + 64][so] = pb1;
    __syncthreads();
    if (kt + 1 < nk) {
      ga0 += 32; ga1 += 32; gb0 += 32; gb1 += 32;
      pa0 = *(const float4*)ga0;
      pa1 = *(const float4*)ga1;
      pb0 = *(const float4*)gb0;
      pb1 = *(const float4*)gb1;
    }
    short8 av[4], bv[4];
#pragma unroll
    for (int i = 0; i < 4; ++i) {
      int row = wm + i * 16 + r16;
      av[i] = *(const short8*)&As[p][row][SWZ(row, kg)];
    }
#pragma unroll
    for (int j = 0; j < 4; ++j) {
      int col = wn + j * 16 + r16;
      bv[j] = *(const short8*)&Bs[p][col][SWZ(col, kg)];
    }
#pragma unroll
    for (int i = 0; i < 4; ++i)
#pragma unroll
      for (int j = 0; j < 4; ++j)
        acc[i][j] = __builtin_amdgcn_mfma_f32_16x16x32_bf16(av[i], bv[j], acc[i][j], 0, 0, 0);
  }

  // epilogue: C/D layout col=lane&15, row=(lane>>4)*4+reg (m89-verified)
  if (C) {
#pragma unroll
    for (int j = 0; j < 4; ++j) {
      int col = bn + wn + j * 16 + r16;
      float bvv = bias ? bias[col] : 0.f;
#pragma unroll
      for (int i = 0; i < 4; ++i) {
        int row0 = bm + wm + i * 16 + kg * 4;
        float* cp = C + (size_t)row0 * N + col;
#pragma unroll
        for (int r = 0; r < 4; ++r)
          cp[(size_t)r * N] = acc[i][j][r] * scale + bvv;
      }
    }
  }
  if (Cb) {
#pragma unroll
    for (int j = 0; j < 4; ++j) {
      int col = bn + wn + j * 16 + r16;
      float bvv = bias ? bias[col] : 0.f;
#pragma unroll
      for (int i = 0; i < 4; ++i) {
        int row0 = bm + wm + i * 16 + kg * 4;
        u16* cp = Cb + (size_t)row0 * N + col;
#pragma unroll
        for (int r = 0; r < 4; ++r)
          cp[(size_t)r * N] = f2bf(acc[i][j][r] * scale + bvv);
      }
    }
  }
}

// ------------- dual-problem GEMM (z selects); problem 0 may emit s1/s2 -----
__global__ __launch_bounds__(256) void gemm_dual(
    const u16* __restrict__ A0, const u16* __restrict__ B00,
    const u16* __restrict__ B01, float* __restrict__ C0, u16* __restrict__ D0,
    const float* __restrict__ e0, const float* __restrict__ f0, int M0, int sp0, float sc0,
    const float* __restrict__ A1v, const float* __restrict__ A2v,
    float* __restrict__ S1o, float* __restrict__ S2o,
    const u16* __restrict__ A1, const u16* __restrict__ B10,
    const u16* __restrict__ B11, float* __restrict__ C1, u16* __restrict__ D1,
    const float* __restrict__ e1, const float* __restrict__ f1, int M1, int sp1, float sc1) {
  const int z = blockIdx.z;
  const u16* A   = z ? A1 : A0;
  const u16* Bt0 = z ? B10 : B00;
  const u16* Bt1 = z ? B11 : B01;
  float* C = z ? C1 : C0;
  u16*   D = z ? D1 : D0;
  const float* bias0 = z ? e1 : e0;
  const float* bias1 = z ? f1 : f0;
  const int M = z ? M1 : M0, split = z ? sp1 : sp0;
  const float scale = z ? sc1 : sc0;
  const int bm = blockIdx.y * 128, bn = blockIdx.x * 128;
  if (bm >= M) return;
  const int N = 1024, K = 1024;
  const u16* Bt = (bm < split) ? Bt0 : Bt1;
  const float* bias = (bm < split) ? bias0 : bias1;

  __shared__ u16 As[2][128][32];
  __shared__ u16 Bs[2][128][32];
  const int tid = threadIdx.x, wave = tid >> 6, lane = tid & 63;
  const int sr = tid >> 2, ss = tid & 3;
  const int so = SWZ(sr, ss);
  const u16* ga0 = A  + (size_t)(bm + sr) * K + ss * 8;
  const u16* ga1 = A  + (size_t)(bm + sr + 64) * K + ss * 8;
  const u16* gb0 = Bt + (size_t)(bn + sr) * K + ss * 8;
  const u16* gb1 = Bt + (size_t)(bn + sr + 64) * K + ss * 8;
  const int r16 = lane & 15, kg = lane >> 4;
  const int wm = (wave >> 1) * 64, wn = (wave & 1) * 64;

  f32x4 acc[4][4] = {};
  const int nk = 32;

  float4 pa0 = *(const float4*)ga0;
  float4 pa1 = *(const float4*)ga1;
  float4 pb0 = *(const float4*)gb0;
  float4 pb1 = *(const float4*)gb1;

  for (int kt = 0; kt < nk; ++kt) {
    const int p = kt & 1;
    *(float4*)&As[p][sr][so]      = pa0;
    *(float4*)&As[p][sr + 64][so] = pa1;
    *(float4*)&Bs[p][sr][so]      = pb0;
    *(float4*)&Bs[p][sr + 64][so] = pb1;
    __syncthreads();
    if (kt + 1 < nk) {
      ga0 += 32; ga1 += 32; gb0 += 32; gb1 += 32;
      pa0 = *(const float4*)ga0;
      pa1 = *(const float4*)ga1;
      pb0 = *(const float4*)gb0;
      pb1 = *(const float4*)gb1;
    }
    short8 av[4], bv[4];
#pragma unroll
    for (int i = 0; i < 4; ++i) {
      int row = wm + i * 16 + r16;
      av[i] = *(const short8*)&As[p][row][SWZ(row, kg)];
    }
#pragma unroll
    for (int j = 0; j < 4; ++j) {
      int col = wn + j * 16 + r16;
      bv[j] = *(const short8*)&Bs[p][col][SWZ(col, kg)];
    }
#pragma unroll
    for (int i = 0; i < 4; ++i)
#pragma unroll
      for (int j = 0; j < 4; ++j)
        acc[i][j] = __builtin_amdgcn_mfma_f32_16x16x32_bf16(av[i], bv[j], acc[i][j], 0, 0, 0);
  }

  if (C) {
#pragma unroll
    for (int j = 0; j < 4; ++j) {
      int col = bn + wn + j * 16 + r16;
      float bvv = bias ? bias[col] : 0.f;
#pragma unroll
      for (int i = 0; i < 4; ++i) {
        int row0 = bm + wm + i * 16 + kg * 4;
        float* cp = C + (size_t)row0 * N + col;
#pragma unroll
        for (int r = 0; r < 4; ++r)
          cp[(size_t)r * N] = acc[i][j][r] * scale + bvv;
      }
    }
  }
  if (D) {
#pragma unroll
    for (int j = 0; j < 4; ++j) {
      int col = bn + wn + j * 16 + r16;
      float bvv = bias ? bias[col] : 0.f;
#pragma unroll
      for (int i = 0; i < 4; ++i) {
        int row0 = bm + wm + i * 16 + kg * 4;
        u16* cp = D + (size_t)row0 * N + col;
#pragma unroll
        for (int r = 0; r < 4; ++r)
          cp[(size_t)r * N] = f2bf(acc[i][j][r] * scale + bvv);
      }
    }
  }

  if (z == 0 && S1o) {
    float c1[4], c2[4];
#pragma unroll
    for (int j = 0; j < 4; ++j) {
      int col = bn + wn + j * 16 + r16;
      c1[j] = A1v[col]; c2[j] = A2v[col];
    }
    float r1[4][4], r2[4][4];
#pragma unroll
    for (int i = 0; i < 4; ++i)
#pragma unroll
      for (int r = 0; r < 4; ++r) {
        float v1 = 0.f, v2 = 0.f;
#pragma unroll
        for (int j = 0; j < 4; ++j) {
          v1 += acc[i][j][r] * c1[j];
          v2 += acc[i][j][r] * c2[j];
        }
#pragma unroll
        for (int off = 8; off; off >>= 1) {
          v1 += __shfl_xor(v1, off, 64);
          v2 += __shfl_xor(v2, off, 64);
        }
        r1[i][r] = v1; r2[i][r] = v2;
      }
    __syncthreads();
    float* sb1 = (float*)&As[0][0][0];
    float* sb2 = sb1 + 256;
    if (r16 == 0) {
      int half = wn >> 6;
#pragma unroll
      for (int i = 0; i < 4; ++i)
#pragma unroll
        for (int r = 0; r < 4; ++r) {
          int row = wm + i * 16 + kg * 4 + r;
          sb1[half * 128 + row] = r1[i][r];
          sb2[half * 128 + row] = r2[i][r];
        }
    }
    __syncthreads();
    if (tid < 128) {
      int h = blockIdx.x;
      S1o[(h << 11) + bm + tid] = sb1[tid] + sb1[128 + tid];
      S2o[(h << 11) + bm + tid] = sb2[tid] + sb2[128 + tid];
    }
  }
}

// ------------- laplacian via G@G^T tiles, fused coalesced dot with lapl ----
// lap = sum_{i,k} L[i,k] * (G G^T)[i,k]. 256 blocks (1/CU), tile 128x128,
// K=1024 (nk=32). Each block dots its OWN L tile (read straight, exactly
// once over the grid). ti = n&15 so A-strip sharers live on one XCD.
// Last block (completion counter) finalizes out[].
__global__ __launch_bounds__(256) void ggt_dot(
    const u16* __restrict__ Gb, const float* __restrict__ L,
    float* __restrict__ acc, int* __restrict__ cnt_done, float* __restrict__ out) {
  __shared__ u16 As[2][128][32];
  __shared__ u16 Bs[2][128][32];
  const int tid = threadIdx.x, wave = tid >> 6, lane = tid & 63;
  const int ti = blockIdx.x & 15, tj = blockIdx.x >> 4;
  const int bm = ti * 128, bn = tj * 128;

  const int sr = tid >> 2, ss = tid & 3;
  const int so = SWZ(sr, ss);
  const u16* ga0 = Gb + (size_t)(bm + sr) * ED + ss * 8;
  const u16* ga1 = Gb + (size_t)(bm + sr + 64) * ED + ss * 8;
  const u16* gb0 = Gb + (size_t)(bn + sr) * ED + ss * 8;
  const u16* gb1 = Gb + (size_t)(bn + sr + 64) * ED + ss * 8;

  const int r16 = lane & 15, kg = lane >> 4;
  const int wm = (wave >> 1) * 64, wn = (wave & 1) * 64;

  f32x4 acc_r[4][4] = {};
  const int nk = 32;

  float4 pa0 = *(const float4*)ga0;
  float4 pa1 = *(const float4*)ga1;
  float4 pb0 = *(const float4*)gb0;
  float4 pb1 = *(const float4*)gb1;

  for (int kt = 0; kt < nk; ++kt) {
    const int p = kt & 1;
    *(float4*)&As[p][sr][so]      = pa0;
    *(float4*)&As[p][sr + 64][so] = pa1;
    *(float4*)&Bs[p][sr][so]      = pb0;
    *(float4*)&Bs[p][sr + 64][so] = pb1;
    __syncthreads();
    if (kt + 1 < nk) {
      ga0 += 32; ga1 += 32; gb0 += 32; gb1 += 32;
      pa0 = *(const float4*)ga0;
      pa1 = *(const float4*)ga1;
      pb0 = *(const float4*)gb0;
      pb1 = *(const float4*)gb1;
    }
    short8 av[4], bv[4];
#pragma unroll
    for (int i = 0; i < 4; ++i) {
      int row = wm + i * 16 + r16;
      av[i] = *(const short8*)&As[p][row][SWZ(row, kg)];
    }
#pragma unroll
    for (int j = 0; j < 4; ++j) {
      int col = wn + j * 16 + r16;
      bv[j] = *(const short8*)&Bs[p][col][SWZ(col, kg)];
    }
#pragma unroll
    for (int i = 0; i < 4; ++i)
#pragma unroll
      for (int j = 0; j < 4; ++j)
        acc_r[i][j] = __builtin_amdgcn_mfma_f32_16x16x32_bf16(av[i], bv[j], acc_r[i][j], 0, 0, 0);
  }

  // fused dot: sum += C_tile[i,k] * L[bm+i, bn+k]  (coalesced 64B/16-lane)
  float sum = 0.f;
#pragma unroll
  for (int i = 0; i < 4; ++i) {
#pragma unroll
    for (int r = 0; r < 4; ++r) {
      int ig = bm + wm + i * 16 + kg * 4 + r;
      const float* lp = L + (size_t)ig * NNODE + bn + wn + r16;
#pragma unroll
      for (int j = 0; j < 4; ++j)
        sum += acc_r[i][j][r] * lp[j * 16];
    }
  }
  sum = blockSum(sum);
  if (tid == 0) {
    atomicAdd(acc, sum);
    __threadfence();
    int prev = atomicAdd(cnt_done, 1);
    if (prev == (int)gridDim.x - 1) {
      float lap  = atomicAdd(acc, 0.f) / 2048.f;
      float info = atomicAdd(acc + 1, 0.f) / 1024.f;
      out[0] = info + 0.1f * lap;
      out[1] = info;
      out[2] = lap;
    }
  }
}

// ------------- fused GAT attention + layer elementwise tail ----------------
__global__ __launch_bounds__(256) void att_elem(
    const u16* __restrict__ WHb, const float* __restrict__ S1,
    const float* __restrict__ S2, const int* __restrict__ nbr,
    const int* __restrict__ ncnt, float* __restrict__ X, u16* __restrict__ Xb,
    const float* __restrict__ g, const float* __restrict__ b,
    int mode, const float* __restrict__ EIN, u16* __restrict__ EOUT,
    const float* __restrict__ g0, const float* __restrict__ b0,
    const float* __restrict__ g1, const float* __restrict__ b1,
    float* __restrict__ acc) {
  const int t = threadIdx.x;
  if (blockIdx.x < NNODE) {
    __shared__ int snb[CAPP];
    __shared__ float pw[NHEAD][CAPP];
    const int n = blockIdx.x;
    const int h = t >> 5, l = t & 31;
    const int cnt = ncnt[n];
    const int cntP = (cnt + 15) & ~15;
    for (int j = t; j < cnt; j += 256) snb[j] = nbr[n * CAP + j];
    __syncthreads();
    for (int j = cnt + t; j < cntP; j += 256) snb[j] = snb[0];

    const float s1v = S1[(h << 11) + n];
    float ev[6];
    float lmax = -1e30f;
    int ne = 0;
    for (int j = l; j < cnt; j += 32) {
      float e = s1v + S2[(h << 11) + snb[j]];
      e = e > 0.f ? e : 0.2f * e;
      ev[ne++] = e;
      lmax = fmaxf(lmax, e);
    }
#pragma unroll
    for (int off = 16; off; off >>= 1) lmax = fmaxf(lmax, __shfl_xor(lmax, off, 64));
    float lsum = 0.f;
    ne = 0;
    for (int j = l; j < cnt; j += 32) {
      float p = __expf(ev[ne++] - lmax);
      pw[h][j] = p;
      lsum += p;
    }
    for (int j = cnt + l; j < cntP; j += 32) pw[h][j] = 0.f;
#pragma unroll
    for (int off = 16; off; off >>= 1) lsum += __shfl_xor(lsum, off, 64);
    const float inv = 1.f / lsum;
    __syncthreads();

    float o0 = 0.f, o1 = 0.f, o2 = 0.f, o3 = 0.f;
    const u16* wp = WHb + (t << 2);
    for (int j0 = 0; j0 < cntP; j0 += 16) {
      ushort4 buf[16];
#pragma unroll
      for (int u = 0; u < 16; ++u)
        buf[u] = *(const ushort4*)(wp + ((size_t)snb[j0 + u] << 10));
#pragma unroll
      for (int u = 0; u < 16; ++u) {
        float w = pw[h][j0 + u];
        o0 += w * bf2f(buf[u].x);
        o1 += w * bf2f(buf[u].y);
        o2 += w * bf2f(buf[u].z);
        o3 += w * bf2f(buf[u].w);
      }
    }
    o0 *= inv; o1 *= inv; o2 *= inv; o3 *= inv;

    float s  = o0 + o1 + o2 + o3;
    float sq = o0 * o0 + o1 * o1 + o2 * o2 + o3 * o3;
    float mean = blockSum(s) * (1.f / 1024.f);
    float var  = blockSum(sq) * (1.f / 1024.f) - mean * mean;
    float rstd = rsqrtf(fmaxf(var, 0.f) + 1e-5f);
    float4 xv = *(float4*)&X[((size_t)n << 10) + (t << 2)];
    float ov[4] = {o0, o1, o2, o3};
    float xa[4] = {xv.x, xv.y, xv.z, xv.w};
#pragma unroll
    for (int i = 0; i < 4; ++i) {
      int c = (t << 2) + i;
      float y = (ov[i] - mean) * rstd * g[c] + b[c];
      y = y > 0.f ? y : expm1f(y);
      xa[i] += y;
    }
    *(float4*)&X[((size_t)n << 10) + (t << 2)] = make_float4(xa[0], xa[1], xa[2], xa[3]);
    ushort4 o;
    o.x = f2bf(xa[0]); o.y = f2bf(xa[1]); o.z = f2bf(xa[2]); o.w = f2bf(xa[3]);
    *(ushort4*)&Xb[((size_t)n << 10) + (t << 2)] = o;
  } else {
    const int row = blockIdx.x - NNODE;
    if (mode == 0) {
      const float* gg = (row < 1024) ? g0 : g1;
      const float* bb = (row < 1024) ? b0 : b1;
      float4 v = *(const float4*)&EIN[((size_t)row << 10) + (t << 2)];
      float s = v.x + v.y + v.z + v.w;
      float sq = v.x * v.x + v.y * v.y + v.z * v.z + v.w * v.w;
      float mean = blockSum(s) * (1.f / 1024.f);
      float var = blockSum(sq) * (1.f / 1024.f) - mean * mean;
      float rstd = rsqrtf(fmaxf(var, 0.f) + 1e-5f);
      float vals[4] = {v.x, v.y, v.z, v.w};
      ushort4 o;
      u16* oa = (u16*)&o;
#pragma unroll
      for (int i = 0; i < 4; ++i) {
        int c = (t << 2) + i;
        float y = (vals[i] - mean) * rstd * gg[c] + bb[c];
        y = 0.5f * y * (1.f + erff(y * 0.70710678118654752f));
        oa[i] = f2bf(y);
      }
      *(ushort4*)&EOUT[((size_t)row << 10) + (t << 2)] = o;
    } else if (mode == 1) {
      float4 v = *(const float4*)&EIN[((size_t)row << 10) + (t << 2)];
      float sq = v.x * v.x + v.y * v.y + v.z * v.z + v.w * v.w;
      float s = blockSum(sq);
      float inv = 1.f / fmaxf(sqrtf(s), 1e-12f);
      ushort4 o;
      o.x = f2bf(v.x * inv); o.y = f2bf(v.y * inv);
      o.z = f2bf(v.z * inv); o.w = f2bf(v.w * inv);
      *(ushort4*)&EOUT[((size_t)row << 10) + (t << 2)] = o;
    } else {
      const float* rw = EIN + ((size_t)row << 10);
      float4 v = *(const float4*)&rw[t << 2];
      float lm = fmaxf(fmaxf(v.x, v.y), fmaxf(v.z, v.w));
      float m = blockMax(lm);
      float ls = __expf(v.x - m) + __expf(v.y - m) + __expf(v.z - m) + __expf(v.w - m);
      float ssum = blockSum(ls);
      if (t == 0) {
        float pos = rw[row];
        float loss = m + logf(ssum + __expf(pos - m)) - pos;
        atomicAdd(acc + 1, loss);
      }
    }
  }
}

// ------------- prep mega-kernel ------------
__global__ __launch_bounds__(256) void prep_mega(
    const float* __restrict__ adj, int* __restrict__ nbr, int* __restrict__ ncnt,
    float* __restrict__ acc, int* __restrict__ cnt_done,
    const float* __restrict__ nodes, float* __restrict__ Xf, u16* __restrict__ Xb,
    const float* __restrict__ q, const float* __restrict__ d, u16* __restrict__ QPb) {
  const int bx = blockIdx.x, tid = threadIdx.x;
  if (bx < NNODE) {
    __shared__ int cnt;
    if (bx == 0 && tid < 2) acc[tid] = 0.f;
    if (bx == 0 && tid == 2) *cnt_done = 0;
    if (tid == 0) cnt = 0;
    __syncthreads();
    for (int c = tid; c < NNODE; c += 256) {
      if (adj[((size_t)bx << 11) + c] > 0.f) {
        int p = atomicAdd(&cnt, 1);
        if (p < CAP) nbr[bx * CAP + p] = c;
      }
    }
    __syncthreads();
    if (tid == 0) ncnt[bx] = cnt < CAP ? cnt : CAP;
  } else if (bx < 2 * NNODE) {
    int i = (bx - NNODE) * 256 + tid;
    float4 v = ((const float4*)nodes)[i];
    ((float4*)Xf)[i] = v;
    ushort4 o;
    o.x = f2bf(v.x); o.y = f2bf(v.y); o.z = f2bf(v.z); o.w = f2bf(v.w);
    ((ushort4*)Xb)[i] = o;
  } else {
    int i = (bx - 2 * NNODE) * 256 + tid;
    const int half = BQ * ED / 4;
    const float* src = (i < half) ? q : d;
    int j = (i < half) ? i : i - half;
    float4 v = ((const float4*)src)[j];
    ushort4 o;
    o.x = f2bf(v.x); o.y = f2bf(v.y); o.z = f2bf(v.z); o.w = f2bf(v.w);
    ((ushort4*)QPb)[i] = o;
  }
}

// ---------------- transposes ----------------
__device__ __forceinline__ void cvt_tr_body(const float* ip, u16* op, int R, int C) {
  __shared__ float T[64][65];
  int r0 = blockIdx.y * 64, c0 = blockIdx.x * 64;
  int t = threadIdx.x;
#pragma unroll
  for (int p = 0; p < 4; ++p) {
    int row = p * 16 + (t >> 4), col = (t & 15) * 4;
    float4 v = *(const float4*)&ip[(size_t)(r0 + row) * C + c0 + col];
    T[row][col] = v.x; T[row][col + 1] = v.y;
    T[row][col + 2] = v.z; T[row][col + 3] = v.w;
  }
  __syncthreads();
#pragma unroll
  for (int p = 0; p < 4; ++p) {
    int c = p * 16 + (t >> 4), r = (t & 15) * 4;
    ushort4 o;
    o.x = f2bf(T[r][c]); o.y = f2bf(T[r + 1][c]);
    o.z = f2bf(T[r + 2][c]); o.w = f2bf(T[r + 3][c]);
    *(ushort4*)&op[(size_t)(c0 + c) * R + r0 + r] = o;
  }
}

__global__ __launch_bounds__(256) void cvt_transpose(
    const float* __restrict__ in, u16* __restrict__ out,
    int R, int C, long inb, long outb) {
  cvt_tr_body(in + (size_t)blockIdx.z * inb, out + (size_t)blockIdx.z * outb, R, C);
}

__global__ __launch_bounds__(256) void cvt_transpose5(
    const float* __restrict__ i0, u16* __restrict__ o0,
    const float* __restrict__ i1, u16* __restrict__ o1,
    const float* __restrict__ i2, u16* __restrict__ o2,
    const float* __restrict__ i3, u16* __restrict__ o3,
    const float* __restrict__ i4, u16* __restrict__ o4) {
  const float* in; u16* out;
  switch (blockIdx.z) {
    case 0: in = i0; out = o0; break;
    case 1: in = i1; out = o1; break;
    case 2: in = i2; out = o2; break;
    case 3: in = i3; out = o3; break;
    default: in = i4; out = o4; break;
  }
  cvt_tr_body(in, out, 1024, 1024);
}

// ---------------- host launcher ----------------
extern "C" void kernel_launch(void* const* d_in, const int* in_sizes, int n_in,
                              void* d_out, int out_size, void* d_ws, size_t ws_size,
                              hipStream_t stream) {
  const float* query = (const float*)d_in[0];
  const float* docs  = (const float*)d_in[1];
  const float* nodes = (const float*)d_in[2];
  const float* adj   = (const float*)d_in[3];
  const float* lapl  = (const float*)d_in[4];
  const float* qW1 = (const float*)d_in[5],  *qb1 = (const float*)d_in[6];
  const float* qg  = (const float*)d_in[7],  *qbt = (const float*)d_in[8];
  const float* qW2 = (const float*)d_in[9],  *qb2 = (const float*)d_in[10];
  const float* dW1 = (const float*)d_in[11], *db1 = (const float*)d_in[12];
  const float* dg  = (const float*)d_in[13], *dbt = (const float*)d_in[14];
  const float* dW2 = (const float*)d_in[15], *db2 = (const float*)d_in[16];
  const float* gatW = (const float*)d_in[17];
  const float* a1   = (const float*)d_in[18];
  const float* a2   = (const float*)d_in[19];
  const float* ln_g = (const float*)d_in[20];
  const float* ln_b = (const float*)d_in[21];
  const float* poW  = (const float*)d_in[22];
  const float* pob  = (const float*)d_in[23];
  float* out = (float*)d_out;

  float* ws = (float*)d_ws;
  float* X    = ws + OFF_X;
  u16*   Xb   = (u16*)(ws + OFF_XB);
  u16*   WHb  = (u16*)(ws + OFF_WHB);
  u16*   WtG  = (u16*)(ws + OFF_WTG);
  u16*   WtPO = (u16*)(ws + OFF_WTPO);
  u16*   WtQ1 = (u16*)(ws + OFF_WTQ1);
  u16*   WtD1 = (u16*)(ws + OFF_WTD1);
  u16*   WtQ2 = (u16*)(ws + OFF_WTQ2);
  u16*   WtD2 = (u16*)(ws + OFF_WTD2);
  u16*   Gb   = (u16*)(ws + OFF_GB);
  u16*   QPb  = (u16*)(ws + OFF_QPB);
  float* Hf   = ws + OFF_HF;
  u16*   Hb   = (u16*)(ws + OFF_HB);
  float* Ff   = ws + OFF_FF;
  u16*   Fb   = (u16*)(ws + OFF_FB);
  float* NEG  = ws + OFF_NEG;
  float* S1v  = ws + OFF_SV1;
  float* S2v  = ws + OFF_SV2;
  float* ACC  = ws + OFF_ACC;
  int*   CNTD = (int*)(ws + OFF_CNT);
  int*   NCNT = (int*)(ws + OFF_NCNT);
  int*   NBR  = (int*)(ws + OFF_NBR);

  const size_t WSL = (size_t)GH * ED;

  // ---- prep (1 launch) + weight transposes (2)
  prep_mega<<<3 * NNODE, 256, 0, stream>>>(
      adj, NBR, NCNT, ACC, CNTD, nodes, X, Xb, query, docs, QPb);
  cvt_transpose<<<dim3(2, 16, 24), 256, 0, stream>>>(
      gatW, WtG, ED, HD, (long)ED * HD, (long)HD * ED);
  cvt_transpose5<<<dim3(16, 16, 5), 256, 0, stream>>>(
      poW, WtPO, qW1, WtQ1, dW1, WtD1, qW2, WtQ2, dW2, WtD2);

  // ---- layer 0: GAT gemm (+s1s2) paired with MLP1; att + ln_gelu merged
  gemm_dual<<<dim3(8, 16, 2), 256, 0, stream>>>(
      Xb, WtG, WtG, nullptr, WHb, nullptr, nullptr, NNODE, NNODE, 1.f,
      a1, a2, S1v, S2v,
      QPb, WtQ1, WtD1, Hf, nullptr, qb1, db1, 2 * BQ, BQ, 1.f);
  att_elem<<<NNODE + 2 * BQ, 256, 0, stream>>>(
      WHb, S1v, S2v, NBR, NCNT, X, Xb, ln_g, ln_b,
      0, Hf, Hb, qg, qbt, dg, dbt, ACC);

  // ---- layer 1: GAT gemm (+s1s2) paired with MLP2; att + l2norm merged
  gemm_dual<<<dim3(8, 16, 2), 256, 0, stream>>>(
      Xb, WtG + WSL, WtG + WSL, nullptr, WHb, nullptr, nullptr, NNODE, NNODE, 1.f,
      a1 + NHEAD * HD, a2 + NHEAD * HD, S1v, S2v,
      Hb, WtQ2, WtD2, Ff, nullptr, qb2, db2, 2 * BQ, BQ, 1.f);
  att_elem<<<NNODE + 2 * BQ, 256, 0, stream>>>(
      WHb, S1v, S2v, NBR, NCNT, X, Xb, ln_g + GH, ln_b + GH,
      1, Ff, Fb, nullptr, nullptr, nullptr, nullptr, ACC);

  // ---- layer 2: GAT gemm (+s1s2) paired with NEG; att + lse merged
  gemm_dual<<<dim3(8, 16, 2), 256, 0, stream>>>(
      Xb, WtG + 2 * WSL, WtG + 2 * WSL, nullptr, WHb, nullptr, nullptr, NNODE, NNODE, 1.f,
      a1 + 2 * NHEAD * HD, a2 + 2 * NHEAD * HD, S1v, S2v,
      Fb, Fb + (size_t)BQ * ED, Fb + (size_t)BQ * ED, NEG, nullptr,
      nullptr, nullptr, BQ, BQ, 20.f);
  att_elem<<<NNODE + BQ, 256, 0, stream>>>(
      WHb, S1v, S2v, NBR, NCNT, X, Xb, ln_g + 2 * GH, ln_b + 2 * GH,
      2, NEG, nullptr, nullptr, nullptr, nullptr, nullptr, ACC);

  // ---- graph embeds (bf16 only) + laplacian via G@G^T (finalize folded)
  gemm128<<<dim3(ED / 128, NNODE / 128), 256, 0, stream>>>(
      Xb, WtPO, WtPO, nullptr, Gb, pob, pob, NNODE, ED, GH, NNODE, 1.f);
  ggt_dot<<<256, 256, 0, stream>>>(Gb, lapl, ACC, CNTD, out);
}

// Round 10
// 353.696 us; speedup vs baseline: 1.0918x; 1.0535x over previous
//
#include <hip/hip_runtime.h>
#include <math.h>

// ---------------- problem constants ----------------
#define ED    1024
#define GH    1024
#define NLAY  3
#define NHEAD 8
#define HD    128
#define NNODE 2048
#define BQ    1024
#define CAP   192
#define CAPP  208

typedef unsigned short u16;
typedef __attribute__((ext_vector_type(8))) short short8;
typedef __attribute__((ext_vector_type(4))) float f32x4;

// ---------------- workspace layout (float units) ----------------
static const size_t OFF_X    = 0;
static const size_t OFF_XB   = 2097152;
static const size_t OFF_WHB  = 3145728;
static const size_t OFF_WTG  = 4194304;
static const size_t OFF_WTPO = 5767168;
static const size_t OFF_WTQ1 = 6291456;
static const size_t OFF_WTD1 = 6815744;
static const size_t OFF_WTQ2 = 7340032;
static const size_t OFF_WTD2 = 7864320;
static const size_t OFF_GB   = 8388608;
static const size_t OFF_QPB  = 11534336;
static const size_t OFF_HF   = 12582912;
static const size_t OFF_HB   = 14680064;
static const size_t OFF_FF   = 15728640;
static const size_t OFF_FB   = 17825792;
static const size_t OFF_NEG  = 18874368;
static const size_t OFF_SV1  = 19922944;
static const size_t OFF_SV2  = 19939328;
static const size_t OFF_ACC  = 19955712;
static const size_t OFF_CNT  = 19955714;
static const size_t OFF_NCNT = 19955720;
static const size_t OFF_NBR  = 19957768;

// ---------------- helpers ----------------
__device__ __forceinline__ u16 f2bf(float f) {
  unsigned int u = __float_as_uint(f);
  return (u16)((u + 0x7fffu + ((u >> 16) & 1u)) >> 16);
}
__device__ __forceinline__ float bf2f(u16 u) {
  return __uint_as_float(((unsigned int)u) << 16);
}

__device__ __forceinline__ float waveSum(float v) {
#pragma unroll
  for (int off = 32; off; off >>= 1) v += __shfl_xor(v, off, 64);
  return v;
}
__device__ __forceinline__ float waveMax(float v) {
#pragma unroll
  for (int off = 32; off; off >>= 1) v = fmaxf(v, __shfl_xor(v, off, 64));
  return v;
}
__device__ __forceinline__ float blockSum(float v) {
  __shared__ float buf[4];
  int lane = threadIdx.x & 63, wid = threadIdx.x >> 6, nw = (blockDim.x + 63) >> 6;
  v = waveSum(v);
  __syncthreads();
  if (lane == 0) buf[wid] = v;
  __syncthreads();
  float r = buf[0];
  for (int i = 1; i < nw; ++i) r += buf[i];
  return r;
}
__device__ __forceinline__ float blockMax(float v) {
  __shared__ float buf[4];
  int lane = threadIdx.x & 63, wid = threadIdx.x >> 6, nw = (blockDim.x + 63) >> 6;
  v = waveMax(v);
  __syncthreads();
  if (lane == 0) buf[wid] = v;
  __syncthreads();
  float r = buf[0];
  for (int i = 1; i < nw; ++i) r = fmaxf(r, buf[i]);
  return r;
}

// LDS seg swizzle (verified 0 bank conflicts)
#define SWZ(row, seg) (((seg) ^ (((row) >> 1) & 3)) << 3)

// ------------- core 128x128 bf16 MFMA GEMM (2-deep prefetch pipeline) ------
__global__ __launch_bounds__(256) void gemm128(
    const u16* __restrict__ A, const u16* __restrict__ B0,
    const u16* __restrict__ B1, float* __restrict__ C, u16* __restrict__ Cb,
    const float* __restrict__ bias0, const float* __restrict__ bias1,
    int M, int N, int K, int split, float scale) {
  __shared__ u16 As[2][128][32];
  __shared__ u16 Bs[2][128][32];
  const int tid = threadIdx.x, wave = tid >> 6, lane = tid & 63;
  const int bm = blockIdx.y * 128, bn = blockIdx.x * 128;
  const u16* Bt = (bm < split) ? B0 : B1;
  const float* bias = (bm < split) ? bias0 : bias1;

  const int sr = tid >> 2, ss = tid & 3;
  const int so = SWZ(sr, ss);
  const u16* ga0 = A  + (size_t)(bm + sr) * K + ss * 8;
  const u16* ga1 = A  + (size_t)(bm + sr + 64) * K + ss * 8;
  const u16* gb0 = Bt + (size_t)(bn + sr) * K + ss * 8;
  const u16* gb1 = Bt + (size_t)(bn + sr + 64) * K + ss * 8;

  const int r16 = lane & 15, kg = lane >> 4;
  const int wm = (wave >> 1) * 64, wn = (wave & 1) * 64;

  f32x4 acc[4][4] = {};
  const int nk = K >> 5;

  // 2-deep prefetch: set X = tile kt (write next), set Y = tile kt+1
  float4 xa0 = *(const float4*)ga0, xa1 = *(const float4*)ga1;
  float4 xb0 = *(const float4*)gb0, xb1 = *(const float4*)gb1;
  ga0 += 32; ga1 += 32; gb0 += 32; gb1 += 32;
  float4 ya0 = *(const float4*)ga0, ya1 = *(const float4*)ga1;
  float4 yb0 = *(const float4*)gb0, yb1 = *(const float4*)gb1;

  for (int kt = 0; kt < nk; ++kt) {
    const int p = kt & 1;
    *(float4*)&As[p][sr][so]      = xa0;
    *(float4*)&As[p][sr + 64][so] = xa1;
    *(float4*)&Bs[p][sr][so]      = xb0;
    *(float4*)&Bs[p][sr + 64][so] = xb1;
    xa0 = ya0; xa1 = ya1; xb0 = yb0; xb1 = yb1;
    if (kt + 2 < nk) {
      ga0 += 32; ga1 += 32; gb0 += 32; gb1 += 32;
      ya0 = *(const float4*)ga0; ya1 = *(const float4*)ga1;
      yb0 = *(const float4*)gb0; yb1 = *(const float4*)gb1;
    }
    __syncthreads();
    short8 av[4], bv[4];
#pragma unroll
    for (int i = 0; i < 4; ++i) {
      int row = wm + i * 16 + r16;
      av[i] = *(const short8*)&As[p][row][SWZ(row, kg)];
    }
#pragma unroll
    for (int j = 0; j < 4; ++j) {
      int col = wn + j * 16 + r16;
      bv[j] = *(const short8*)&Bs[p][col][SWZ(col, kg)];
    }
#pragma unroll
    for (int i = 0; i < 4; ++i)
#pragma unroll
      for (int j = 0; j < 4; ++j)
        acc[i][j] = __builtin_amdgcn_mfma_f32_16x16x32_bf16(av[i], bv[j], acc[i][j], 0, 0, 0);
  }

  if (C) {
#pragma unroll
    for (int j = 0; j < 4; ++j) {
      int col = bn + wn + j * 16 + r16;
      float bvv = bias ? bias[col] : 0.f;
#pragma unroll
      for (int i = 0; i < 4; ++i) {
        int row0 = bm + wm + i * 16 + kg * 4;
        float* cp = C + (size_t)row0 * N + col;
#pragma unroll
        for (int r = 0; r < 4; ++r)
          cp[(size_t)r * N] = acc[i][j][r] * scale + bvv;
      }
    }
  }
  if (Cb) {
#pragma unroll
    for (int j = 0; j < 4; ++j) {
      int col = bn + wn + j * 16 + r16;
      float bvv = bias ? bias[col] : 0.f;
#pragma unroll
      for (int i = 0; i < 4; ++i) {
        int row0 = bm + wm + i * 16 + kg * 4;
        u16* cp = Cb + (size_t)row0 * N + col;
#pragma unroll
        for (int r = 0; r < 4; ++r)
          cp[(size_t)r * N] = f2bf(acc[i][j][r] * scale + bvv);
      }
    }
  }
}

// ------------- dual-problem GEMM (2-deep prefetch); z=0 may emit s1/s2 -----
__global__ __launch_bounds__(256) void gemm_dual(
    const u16* __restrict__ A0, const u16* __restrict__ B00,
    const u16* __restrict__ B01, float* __restrict__ C0, u16* __restrict__ D0,
    const float* __restrict__ e0, const float* __restrict__ f0, int M0, int sp0, float sc0,
    const float* __restrict__ A1v, const float* __restrict__ A2v,
    float* __restrict__ S1o, float* __restrict__ S2o,
    const u16* __restrict__ A1, const u16* __restrict__ B10,
    const u16* __restrict__ B11, float* __restrict__ C1, u16* __restrict__ D1,
    const float* __restrict__ e1, const float* __restrict__ f1, int M1, int sp1, float sc1) {
  const int z = blockIdx.z;
  const u16* A   = z ? A1 : A0;
  const u16* Bt0 = z ? B10 : B00;
  const u16* Bt1 = z ? B11 : B01;
  float* C = z ? C1 : C0;
  u16*   D = z ? D1 : D0;
  const float* bias0 = z ? e1 : e0;
  const float* bias1 = z ? f1 : f0;
  const int M = z ? M1 : M0, split = z ? sp1 : sp0;
  const float scale = z ? sc1 : sc0;
  const int bm = blockIdx.y * 128, bn = blockIdx.x * 128;
  if (bm >= M) return;
  const int N = 1024, K = 1024;
  const u16* Bt = (bm < split) ? Bt0 : Bt1;
  const float* bias = (bm < split) ? bias0 : bias1;

  __shared__ u16 As[2][128][32];
  __shared__ u16 Bs[2][128][32];
  const int tid = threadIdx.x, wave = tid >> 6, lane = tid & 63;
  const int sr = tid >> 2, ss = tid & 3;
  const int so = SWZ(sr, ss);
  const u16* ga0 = A  + (size_t)(bm + sr) * K + ss * 8;
  const u16* ga1 = A  + (size_t)(bm + sr + 64) * K + ss * 8;
  const u16* gb0 = Bt + (size_t)(bn + sr) * K + ss * 8;
  const u16* gb1 = Bt + (size_t)(bn + sr + 64) * K + ss * 8;
  const int r16 = lane & 15, kg = lane >> 4;
  const int wm = (wave >> 1) * 64, wn = (wave & 1) * 64;

  f32x4 acc[4][4] = {};
  const int nk = 32;

  float4 xa0 = *(const float4*)ga0, xa1 = *(const float4*)ga1;
  float4 xb0 = *(const float4*)gb0, xb1 = *(const float4*)gb1;
  ga0 += 32; ga1 += 32; gb0 += 32; gb1 += 32;
  float4 ya0 = *(const float4*)ga0, ya1 = *(const float4*)ga1;
  float4 yb0 = *(const float4*)gb0, yb1 = *(const float4*)gb1;

  for (int kt = 0; kt < nk; ++kt) {
    const int p = kt & 1;
    *(float4*)&As[p][sr][so]      = xa0;
    *(float4*)&As[p][sr + 64][so] = xa1;
    *(float4*)&Bs[p][sr][so]      = xb0;
    *(float4*)&Bs[p][sr + 64][so] = xb1;
    xa0 = ya0; xa1 = ya1; xb0 = yb0; xb1 = yb1;
    if (kt + 2 < nk) {
      ga0 += 32; ga1 += 32; gb0 += 32; gb1 += 32;
      ya0 = *(const float4*)ga0; ya1 = *(const float4*)ga1;
      yb0 = *(const float4*)gb0; yb1 = *(const float4*)gb1;
    }
    __syncthreads();
    short8 av[4], bv[4];
#pragma unroll
    for (int i = 0; i < 4; ++i) {
      int row = wm + i * 16 + r16;
      av[i] = *(const short8*)&As[p][row][SWZ(row, kg)];
    }
#pragma unroll
    for (int j = 0; j < 4; ++j) {
      int col = wn + j * 16 + r16;
      bv[j] = *(const short8*)&Bs[p][col][SWZ(col, kg)];
    }
#pragma unroll
    for (int i = 0; i < 4; ++i)
#pragma unroll
      for (int j = 0; j < 4; ++j)
        acc[i][j] = __builtin_amdgcn_mfma_f32_16x16x32_bf16(av[i], bv[j], acc[i][j], 0, 0, 0);
  }

  if (C) {
#pragma unroll
    for (int j = 0; j < 4; ++j) {
      int col = bn + wn + j * 16 + r16;
      float bvv = bias ? bias[col] : 0.f;
#pragma unroll
      for (int i = 0; i < 4; ++i) {
        int row0 = bm + wm + i * 16 + kg * 4;
        float* cp = C + (size_t)row0 * N + col;
#pragma unroll
        for (int r = 0; r < 4; ++r)
          cp[(size_t)r * N] = acc[i][j][r] * scale + bvv;
      }
    }
  }
  if (D) {
#pragma unroll
    for (int j = 0; j < 4; ++j) {
      int col = bn + wn + j * 16 + r16;
      float bvv = bias ? bias[col] : 0.f;
#pragma unroll
      for (int i = 0; i < 4; ++i) {
        int row0 = bm + wm + i * 16 + kg * 4;
        u16* cp = D + (size_t)row0 * N + col;
#pragma unroll
        for (int r = 0; r < 4; ++r)
          cp[(size_t)r * N] = f2bf(acc[i][j][r] * scale + bvv);
      }
    }
  }

  if (z == 0 && S1o) {
    float c1[4], c2[4];
#pragma unroll
    for (int j = 0; j < 4; ++j) {
      int col = bn + wn + j * 16 + r16;
      c1[j] = A1v[col]; c2[j] = A2v[col];
    }
    float r1[4][4], r2[4][4];
#pragma unroll
    for (int i = 0; i < 4; ++i)
#pragma unroll
      for (int r = 0; r < 4; ++r) {
        float v1 = 0.f, v2 = 0.f;
#pragma unroll
        for (int j = 0; j < 4; ++j) {
          v1 += acc[i][j][r] * c1[j];
          v2 += acc[i][j][r] * c2[j];
        }
#pragma unroll
        for (int off = 8; off; off >>= 1) {
          v1 += __shfl_xor(v1, off, 64);
          v2 += __shfl_xor(v2, off, 64);
        }
        r1[i][r] = v1; r2[i][r] = v2;
      }
    __syncthreads();
    float* sb1 = (float*)&As[0][0][0];
    float* sb2 = sb1 + 256;
    if (r16 == 0) {
      int half = wn >> 6;
#pragma unroll
      for (int i = 0; i < 4; ++i)
#pragma unroll
        for (int r = 0; r < 4; ++r) {
          int row = wm + i * 16 + kg * 4 + r;
          sb1[half * 128 + row] = r1[i][r];
          sb2[half * 128 + row] = r2[i][r];
        }
    }
    __syncthreads();
    if (tid < 128) {
      int h = blockIdx.x;
      S1o[(h << 11) + bm + tid] = sb1[tid] + sb1[128 + tid];
      S2o[(h << 11) + bm + tid] = sb2[tid] + sb2[128 + tid];
    }
  }
}

// ------------- laplacian via partial G@G^T tiles (split-K=2) ---------------
// sum = Σ L∘C; C = Σ_halves C_partial (linear). Grid (256, 2): y = K-half.
// 512 blocks = 2/CU. Each block dots its partial tile against L (coalesced).
__global__ __launch_bounds__(256) void ggt_dot(
    const u16* __restrict__ Gb, const float* __restrict__ L,
    float* __restrict__ acc, int* __restrict__ cnt_done, float* __restrict__ out) {
  __shared__ u16 As[2][128][32];
  __shared__ u16 Bs[2][128][32];
  const int tid = threadIdx.x, wave = tid >> 6, lane = tid & 63;
  const int ti = blockIdx.x & 15, tj = blockIdx.x >> 4;
  const int bm = ti * 128, bn = tj * 128;
  const int k0 = blockIdx.y * 512;

  const int sr = tid >> 2, ss = tid & 3;
  const int so = SWZ(sr, ss);
  const u16* ga0 = Gb + (size_t)(bm + sr) * ED + k0 + ss * 8;
  const u16* ga1 = Gb + (size_t)(bm + sr + 64) * ED + k0 + ss * 8;
  const u16* gb0 = Gb + (size_t)(bn + sr) * ED + k0 + ss * 8;
  const u16* gb1 = Gb + (size_t)(bn + sr + 64) * ED + k0 + ss * 8;

  const int r16 = lane & 15, kg = lane >> 4;
  const int wm = (wave >> 1) * 64, wn = (wave & 1) * 64;

  f32x4 acc_r[4][4] = {};
  const int nk = 16;

  float4 xa0 = *(const float4*)ga0, xa1 = *(const float4*)ga1;
  float4 xb0 = *(const float4*)gb0, xb1 = *(const float4*)gb1;
  ga0 += 32; ga1 += 32; gb0 += 32; gb1 += 32;
  float4 ya0 = *(const float4*)ga0, ya1 = *(const float4*)ga1;
  float4 yb0 = *(const float4*)gb0, yb1 = *(const float4*)gb1;

  for (int kt = 0; kt < nk; ++kt) {
    const int p = kt & 1;
    *(float4*)&As[p][sr][so]      = xa0;
    *(float4*)&As[p][sr + 64][so] = xa1;
    *(float4*)&Bs[p][sr][so]      = xb0;
    *(float4*)&Bs[p][sr + 64][so] = xb1;
    xa0 = ya0; xa1 = ya1; xb0 = yb0; xb1 = yb1;
    if (kt + 2 < nk) {
      ga0 += 32; ga1 += 32; gb0 += 32; gb1 += 32;
      ya0 = *(const float4*)ga0; ya1 = *(const float4*)ga1;
      yb0 = *(const float4*)gb0; yb1 = *(const float4*)gb1;
    }
    __syncthreads();
    short8 av[4], bv[4];
#pragma unroll
    for (int i = 0; i < 4; ++i) {
      int row = wm + i * 16 + r16;
      av[i] = *(const short8*)&As[p][row][SWZ(row, kg)];
    }
#pragma unroll
    for (int j = 0; j < 4; ++j) {
      int col = wn + j * 16 + r16;
      bv[j] = *(const short8*)&Bs[p][col][SWZ(col, kg)];
    }
#pragma unroll
    for (int i = 0; i < 4; ++i)
#pragma unroll
      for (int j = 0; j < 4; ++j)
        acc_r[i][j] = __builtin_amdgcn_mfma_f32_16x16x32_bf16(av[i], bv[j], acc_r[i][j], 0, 0, 0);
  }

  float sum = 0.f;
#pragma unroll
  for (int i = 0; i < 4; ++i) {
#pragma unroll
    for (int r = 0; r < 4; ++r) {
      int ig = bm + wm + i * 16 + kg * 4 + r;
      const float* lp = L + (size_t)ig * NNODE + bn + wn + r16;
#pragma unroll
      for (int j = 0; j < 4; ++j)
        sum += acc_r[i][j][r] * lp[j * 16];
    }
  }
  sum = blockSum(sum);
  if (tid == 0) {
    atomicAdd(acc, sum);
    __threadfence();
    int prev = atomicAdd(cnt_done, 1);
    if (prev == (int)(gridDim.x * gridDim.y) - 1) {
      float lap  = atomicAdd(acc, 0.f) / 2048.f;
      float info = atomicAdd(acc + 1, 0.f) / 1024.f;
      out[0] = info + 0.1f * lap;
      out[1] = info;
      out[2] = lap;
    }
  }
}

// ------------- fused GAT attention + layer elementwise tail ----------------
__global__ __launch_bounds__(256) void att_elem(
    const u16* __restrict__ WHb, const float* __restrict__ S1,
    const float* __restrict__ S2, const int* __restrict__ nbr,
    const int* __restrict__ ncnt, float* __restrict__ X, u16* __restrict__ Xb,
    const float* __restrict__ g, const float* __restrict__ b,
    int mode, const float* __restrict__ EIN, u16* __restrict__ EOUT,
    const float* __restrict__ g0, const float* __restrict__ b0,
    const float* __restrict__ g1, const float* __restrict__ b1,
    float* __restrict__ acc) {
  const int t = threadIdx.x;
  if (blockIdx.x < NNODE) {
    __shared__ int snb[CAPP];
    __shared__ float pw[NHEAD][CAPP];
    const int n = blockIdx.x;
    const int h = t >> 5, l = t & 31;
    const int cnt = ncnt[n];
    const int cntP = (cnt + 15) & ~15;
    for (int j = t; j < cnt; j += 256) snb[j] = nbr[n * CAP + j];
    __syncthreads();
    for (int j = cnt + t; j < cntP; j += 256) snb[j] = snb[0];

    const float s1v = S1[(h << 11) + n];
    float ev[6];
    float lmax = -1e30f;
    int ne = 0;
    for (int j = l; j < cnt; j += 32) {
      float e = s1v + S2[(h << 11) + snb[j]];
      e = e > 0.f ? e : 0.2f * e;
      ev[ne++] = e;
      lmax = fmaxf(lmax, e);
    }
#pragma unroll
    for (int off = 16; off; off >>= 1) lmax = fmaxf(lmax, __shfl_xor(lmax, off, 64));
    float lsum = 0.f;
    ne = 0;
    for (int j = l; j < cnt; j += 32) {
      float p = __expf(ev[ne++] - lmax);
      pw[h][j] = p;
      lsum += p;
    }
    for (int j = cnt + l; j < cntP; j += 32) pw[h][j] = 0.f;
#pragma unroll
    for (int off = 16; off; off >>= 1) lsum += __shfl_xor(lsum, off, 64);
    const float inv = 1.f / lsum;
    __syncthreads();

    float o0 = 0.f, o1 = 0.f, o2 = 0.f, o3 = 0.f;
    const u16* wp = WHb + (t << 2);
    for (int j0 = 0; j0 < cntP; j0 += 16) {
      ushort4 buf[16];
#pragma unroll
      for (int u = 0; u < 16; ++u)
        buf[u] = *(const ushort4*)(wp + ((size_t)snb[j0 + u] << 10));
#pragma unroll
      for (int u = 0; u < 16; ++u) {
        float w = pw[h][j0 + u];
        o0 += w * bf2f(buf[u].x);
        o1 += w * bf2f(buf[u].y);
        o2 += w * bf2f(buf[u].z);
        o3 += w * bf2f(buf[u].w);
      }
    }
    o0 *= inv; o1 *= inv; o2 *= inv; o3 *= inv;

    float s  = o0 + o1 + o2 + o3;
    float sq = o0 * o0 + o1 * o1 + o2 * o2 + o3 * o3;
    float mean = blockSum(s) * (1.f / 1024.f);
    float var  = blockSum(sq) * (1.f / 1024.f) - mean * mean;
    float rstd = rsqrtf(fmaxf(var, 0.f) + 1e-5f);
    float4 xv = *(float4*)&X[((size_t)n << 10) + (t << 2)];
    float ov[4] = {o0, o1, o2, o3};
    float xa[4] = {xv.x, xv.y, xv.z, xv.w};
#pragma unroll
    for (int i = 0; i < 4; ++i) {
      int c = (t << 2) + i;
      float y = (ov[i] - mean) * rstd * g[c] + b[c];
      y = y > 0.f ? y : expm1f(y);
      xa[i] += y;
    }
    *(float4*)&X[((size_t)n << 10) + (t << 2)] = make_float4(xa[0], xa[1], xa[2], xa[3]);
    ushort4 o;
    o.x = f2bf(xa[0]); o.y = f2bf(xa[1]); o.z = f2bf(xa[2]); o.w = f2bf(xa[3]);
    *(ushort4*)&Xb[((size_t)n << 10) + (t << 2)] = o;
  } else {
    const int row = blockIdx.x - NNODE;
    if (mode == 0) {
      const float* gg = (row < 1024) ? g0 : g1;
      const float* bb = (row < 1024) ? b0 : b1;
      float4 v = *(const float4*)&EIN[((size_t)row << 10) + (t << 2)];
      float s = v.x + v.y + v.z + v.w;
      float sq = v.x * v.x + v.y * v.y + v.z * v.z + v.w * v.w;
      float mean = blockSum(s) * (1.f / 1024.f);
      float var = blockSum(sq) * (1.f / 1024.f) - mean * mean;
      float rstd = rsqrtf(fmaxf(var, 0.f) + 1e-5f);
      float vals[4] = {v.x, v.y, v.z, v.w};
      ushort4 o;
      u16* oa = (u16*)&o;
#pragma unroll
      for (int i = 0; i < 4; ++i) {
        int c = (t << 2) + i;
        float y = (vals[i] - mean) * rstd * gg[c] + bb[c];
        y = 0.5f * y * (1.f + erff(y * 0.70710678118654752f));
        oa[i] = f2bf(y);
      }
      *(ushort4*)&EOUT[((size_t)row << 10) + (t << 2)] = o;
    } else if (mode == 1) {
      float4 v = *(const float4*)&EIN[((size_t)row << 10) + (t << 2)];
      float sq = v.x * v.x + v.y * v.y + v.z * v.z + v.w * v.w;
      float s = blockSum(sq);
      float inv = 1.f / fmaxf(sqrtf(s), 1e-12f);
      ushort4 o;
      o.x = f2bf(v.x * inv); o.y = f2bf(v.y * inv);
      o.z = f2bf(v.z * inv); o.w = f2bf(v.w * inv);
      *(ushort4*)&EOUT[((size_t)row << 10) + (t << 2)] = o;
    } else {
      const float* rw = EIN + ((size_t)row << 10);
      float4 v = *(const float4*)&rw[t << 2];
      float lm = fmaxf(fmaxf(v.x, v.y), fmaxf(v.z, v.w));
      float m = blockMax(lm);
      float ls = __expf(v.x - m) + __expf(v.y - m) + __expf(v.z - m) + __expf(v.w - m);
      float ssum = blockSum(ls);
      if (t == 0) {
        float pos = rw[row];
        float loss = m + logf(ssum + __expf(pos - m)) - pos;
        atomicAdd(acc + 1, loss);
      }
    }
  }
}

// ------------- prep mega-kernel ------------
__global__ __launch_bounds__(256) void prep_mega(
    const float* __restrict__ adj, int* __restrict__ nbr, int* __restrict__ ncnt,
    float* __restrict__ acc, int* __restrict__ cnt_done,
    const float* __restrict__ nodes, float* __restrict__ Xf, u16* __restrict__ Xb,
    const float* __restrict__ q, const float* __restrict__ d, u16* __restrict__ QPb) {
  const int bx = blockIdx.x, tid = threadIdx.x;
  if (bx < NNODE) {
    __shared__ int cnt;
    if (bx == 0 && tid < 2) acc[tid] = 0.f;
    if (bx == 0 && tid == 2) *cnt_done = 0;
    if (tid == 0) cnt = 0;
    __syncthreads();
    for (int c = tid; c < NNODE; c += 256) {
      if (adj[((size_t)bx << 11) + c] > 0.f) {
        int p = atomicAdd(&cnt, 1);
        if (p < CAP) nbr[bx * CAP + p] = c;
      }
    }
    __syncthreads();
    if (tid == 0) ncnt[bx] = cnt < CAP ? cnt : CAP;
  } else if (bx < 2 * NNODE) {
    int i = (bx - NNODE) * 256 + tid;
    float4 v = ((const float4*)nodes)[i];
    ((float4*)Xf)[i] = v;
    ushort4 o;
    o.x = f2bf(v.x); o.y = f2bf(v.y); o.z = f2bf(v.z); o.w = f2bf(v.w);
    ((ushort4*)Xb)[i] = o;
  } else {
    int i = (bx - 2 * NNODE) * 256 + tid;
    const int half = BQ * ED / 4;
    const float* src = (i < half) ? q : d;
    int j = (i < half) ? i : i - half;
    float4 v = ((const float4*)src)[j];
    ushort4 o;
    o.x = f2bf(v.x); o.y = f2bf(v.y); o.z = f2bf(v.z); o.w = f2bf(v.w);
    ((ushort4*)QPb)[i] = o;
  }
}

// ---------------- transposes ----------------
__device__ __forceinline__ void cvt_tr_body(const float* ip, u16* op, int R, int C) {
  __shared__ float T[64][65];
  int r0 = blockIdx.y * 64, c0 = blockIdx.x * 64;
  int t = threadIdx.x;
#pragma unroll
  for (int p = 0; p < 4; ++p) {
    int row = p * 16 + (t >> 4), col = (t & 15) * 4;
    float4 v = *(const float4*)&ip[(size_t)(r0 + row) * C + c0 + col];
    T[row][col] = v.x; T[row][col + 1] = v.y;
    T[row][col + 2] = v.z; T[row][col + 3] = v.w;
  }
  __syncthreads();
#pragma unroll
  for (int p = 0; p < 4; ++p) {
    int c = p * 16 + (t >> 4), r = (t & 15) * 4;
    ushort4 o;
    o.x = f2bf(T[r][c]); o.y = f2bf(T[r + 1][c]);
    o.z = f2bf(T[r + 2][c]); o.w = f2bf(T[r + 3][c]);
    *(ushort4*)&op[(size_t)(c0 + c) * R + r0 + r] = o;
  }
}

__global__ __launch_bounds__(256) void cvt_transpose(
    const float* __restrict__ in, u16* __restrict__ out,
    int R, int C, long inb, long outb) {
  cvt_tr_body(in + (size_t)blockIdx.z * inb, out + (size_t)blockIdx.z * outb, R, C);
}

__global__ __launch_bounds__(256) void cvt_transpose5(
    const float* __restrict__ i0, u16* __restrict__ o0,
    const float* __restrict__ i1, u16* __restrict__ o1,
    const float* __restrict__ i2, u16* __restrict__ o2,
    const float* __restrict__ i3, u16* __restrict__ o3,
    const float* __restrict__ i4, u16* __restrict__ o4) {
  const float* in; u16* out;
  switch (blockIdx.z) {
    case 0: in = i0; out = o0; break;
    case 1: in = i1; out = o1; break;
    case 2: in = i2; out = o2; break;
    case 3: in = i3; out = o3; break;
    default: in = i4; out = o4; break;
  }
  cvt_tr_body(in, out, 1024, 1024);
}

// ---------------- host launcher ----------------
extern "C" void kernel_launch(void* const* d_in, const int* in_sizes, int n_in,
                              void* d_out, int out_size, void* d_ws, size_t ws_size,
                              hipStream_t stream) {
  const float* query = (const float*)d_in[0];
  const float* docs  = (const float*)d_in[1];
  const float* nodes = (const float*)d_in[2];
  const float* adj   = (const float*)d_in[3];
  const float* lapl  = (const float*)d_in[4];
  const float* qW1 = (const float*)d_in[5],  *qb1 = (const float*)d_in[6];
  const float* qg  = (const float*)d_in[7],  *qbt = (const float*)d_in[8];
  const float* qW2 = (const float*)d_in[9],  *qb2 = (const float*)d_in[10];
  const float* dW1 = (const float*)d_in[11], *db1 = (const float*)d_in[12];
  const float* dg  = (const float*)d_in[13], *dbt = (const float*)d_in[14];
  const float* dW2 = (const float*)d_in[15], *db2 = (const float*)d_in[16];
  const float* gatW = (const float*)d_in[17];
  const float* a1   = (const float*)d_in[18];
  const float* a2   = (const float*)d_in[19];
  const float* ln_g = (const float*)d_in[20];
  const float* ln_b = (const float*)d_in[21];
  const float* poW  = (const float*)d_in[22];
  const float* pob  = (const float*)d_in[23];
  float* out = (float*)d_out;

  float* ws = (float*)d_ws;
  float* X    = ws + OFF_X;
  u16*   Xb   = (u16*)(ws + OFF_XB);
  u16*   WHb  = (u16*)(ws + OFF_WHB);
  u16*   WtG  = (u16*)(ws + OFF_WTG);
  u16*   WtPO = (u16*)(ws + OFF_WTPO);
  u16*   WtQ1 = (u16*)(ws + OFF_WTQ1);
  u16*   WtD1 = (u16*)(ws + OFF_WTD1);
  u16*   WtQ2 = (u16*)(ws + OFF_WTQ2);
  u16*   WtD2 = (u16*)(ws + OFF_WTD2);
  u16*   Gb   = (u16*)(ws + OFF_GB);
  u16*   QPb  = (u16*)(ws + OFF_QPB);
  float* Hf   = ws + OFF_HF;
  u16*   Hb   = (u16*)(ws + OFF_HB);
  float* Ff   = ws + OFF_FF;
  u16*   Fb   = (u16*)(ws + OFF_FB);
  float* NEG  = ws + OFF_NEG;
  float* S1v  = ws + OFF_SV1;
  float* S2v  = ws + OFF_SV2;
  float* ACC  = ws + OFF_ACC;
  int*   CNTD = (int*)(ws + OFF_CNT);
  int*   NCNT = (int*)(ws + OFF_NCNT);
  int*   NBR  = (int*)(ws + OFF_NBR);

  const size_t WSL = (size_t)GH * ED;

  prep_mega<<<3 * NNODE, 256, 0, stream>>>(
      adj, NBR, NCNT, ACC, CNTD, nodes, X, Xb, query, docs, QPb);
  cvt_transpose<<<dim3(2, 16, 24), 256, 0, stream>>>(
      gatW, WtG, ED, HD, (long)ED * HD, (long)HD * ED);
  cvt_transpose5<<<dim3(16, 16, 5), 256, 0, stream>>>(
      poW, WtPO, qW1, WtQ1, dW1, WtD1, qW2, WtQ2, dW2, WtD2);

  gemm_dual<<<dim3(8, 16, 2), 256, 0, stream>>>(
      Xb, WtG, WtG, nullptr, WHb, nullptr, nullptr, NNODE, NNODE, 1.f,
      a1, a2, S1v, S2v,
      QPb, WtQ1, WtD1, Hf, nullptr, qb1, db1, 2 * BQ, BQ, 1.f);
  att_elem<<<NNODE + 2 * BQ, 256, 0, stream>>>(
      WHb, S1v, S2v, NBR, NCNT, X, Xb, ln_g, ln_b,
      0, Hf, Hb, qg, qbt, dg, dbt, ACC);

  gemm_dual<<<dim3(8, 16, 2), 256, 0, stream>>>(
      Xb, WtG + WSL, WtG + WSL, nullptr, WHb, nullptr, nullptr, NNODE, NNODE, 1.f,
      a1 + NHEAD * HD, a2 + NHEAD * HD, S1v, S2v,
      Hb, WtQ2, WtD2, Ff, nullptr, qb2, db2, 2 * BQ, BQ, 1.f);
  att_elem<<<NNODE + 2 * BQ, 256, 0, stream>>>(
      WHb, S1v, S2v, NBR, NCNT, X, Xb, ln_g + GH, ln_b + GH,
      1, Ff, Fb, nullptr, nullptr, nullptr, nullptr, ACC);

  gemm_dual<<<dim3(8, 16, 2), 256, 0, stream>>>(
      Xb, WtG + 2 * WSL, WtG + 2 * WSL, nullptr, WHb, nullptr, nullptr, NNODE, NNODE, 1.f,
      a1 + 2 * NHEAD * HD, a2 + 2 * NHEAD * HD, S1v, S2v,
      Fb, Fb + (size_t)BQ * ED, Fb + (size_t)BQ * ED, NEG, nullptr,
      nullptr, nullptr, BQ, BQ, 20.f);
  att_elem<<<NNODE + BQ, 256, 0, stream>>>(
      WHb, S1v, S2v, NBR, NCNT, X, Xb, ln_g + 2 * GH, ln_b + 2 * GH,
      2, NEG, nullptr, nullptr, nullptr, nullptr, nullptr, ACC);

  gemm128<<<dim3(ED / 128, NNODE / 128), 256, 0, stream>>>(
      Xb, WtPO, WtPO, nullptr, Gb, pob, pob, NNODE, ED, GH, NNODE, 1.f);
  ggt_dot<<<dim3(256, 2), 256, 0, stream>>>(Gb, lapl, ACC, CNTD, out);
}